// Round 4
// baseline (1238.459 us; speedup 1.0000x reference)
//
#include <hip/hip_runtime.h>

#define NV 200000
#define NDN 25000
#define EPSV 1e-5f

typedef short bf16x8 __attribute__((ext_vector_type(8)));
typedef float f32x16 __attribute__((ext_vector_type(16)));

static __device__ __forceinline__ float silu_f(float v) { return v / (1.0f + __expf(-v)); }
static __device__ __forceinline__ unsigned short f2b(float f) {
    unsigned u = __float_as_uint(f);
    return (unsigned short)((u + 0x7FFFu + ((u >> 16) & 1u)) >> 16);
}
static __device__ __forceinline__ float b2f(unsigned short h) {
    return __uint_as_float(((unsigned)h) << 16);
}
static __device__ __forceinline__ bf16x8 bc8(uint4 v) { return __builtin_bit_cast(bf16x8, v); }
#define MFMA32(a, b, c) __builtin_amdgcn_mfma_f32_32x32x16_bf16(a, b, c, 0, 0, 0)

// workspace byte offsets
#define OFF_STATS1 0                               // 128 f32 (sum[64], sumsq[64])
#define OFF_STATS2 512                             // 256 f32
#define OFF_TP     4096                            // 16*256 f32
#define OFF_W1B    32768                           // bf16 swizzled 27*64*128
#define OFF_W2B    (OFF_W1B + 27 * 64 * 128 * 2)   // 27*128*128
#define OFF_WDB    (OFF_W2B + 27 * 128 * 128 * 2)  // 8*128*128
#define OFF_WIDB   (OFF_WDB + 8 * 128 * 128 * 2)   // 64*128
#define OFF_H1     (2u << 20)                      // bf16 (NV+1)*64  (row NV = zeros)
#define OFF_H2     (28u << 20)                     // bf16 (NV+1)*128 (row NV = zeros; h2 then h3 in place)
#define OFF_H4     (80u << 20)                     // bf16 NV*128

// ---------------- small kernels ----------------

__global__ void k_zero(float* p) {
    int i = threadIdx.x;
    if (i < 384) p[i] = 0.0f;
}

// zero row NV of H1 (64 bf16) and H2 (128 bf16) — gather target for missing neighbors
__global__ void k_zrow(unsigned short* H1, unsigned short* H2) {
    int t = threadIdx.x;    // 128 threads
    if (t < 64) H1[(long)NV * 64 + t] = 0;
    H2[(long)NV * 128 + t] = 0;
}

__global__ __launch_bounds__(256) void k_stats1(const float* __restrict__ x,
                                                float* __restrict__ stats) {
    int c = threadIdx.x & 63;
    int r0 = blockIdx.x * 4 + (threadIdx.x >> 6);
    float s = 0.f, q = 0.f;
    for (int r = r0; r < NV; r += gridDim.x * 4) {
        float v = x[r * 64 + c];
        s += v; q += v * v;
    }
    __shared__ float rs[256], rq[256];
    rs[threadIdx.x] = s; rq[threadIdx.x] = q;
    __syncthreads();
    if (threadIdx.x < 64) {
        s = rs[threadIdx.x] + rs[threadIdx.x + 64] + rs[threadIdx.x + 128] + rs[threadIdx.x + 192];
        q = rq[threadIdx.x] + rq[threadIdx.x + 64] + rq[threadIdx.x + 128] + rq[threadIdx.x + 192];
        atomicAdd(&stats[c], s);
        atomicAdd(&stats[64 + c], q);
    }
}

__global__ __launch_bounds__(256) void k_tp(const float* __restrict__ t,
                                            const float* __restrict__ Wt,
                                            const float* __restrict__ bt,
                                            float* __restrict__ tp) {
    __shared__ float st[256];
    int b = blockIdx.x, o = threadIdx.x;
    st[o] = silu_f(t[b * 256 + o]);
    __syncthreads();
    float acc = bt[o];
    for (int e = 0; e < 256; e++) acc += st[e] * Wt[e * 256 + o];
    tp[b * 256 + o] = acc;
}

// convert weights fp32 [K][CI][128] -> bf16 fragment-order units:
// unit u = ((k*S + s)*4 + nt)*64 + lane ; elem j: W[k][s*16 + (lane>>5)*8 + j][nt*32 + (lane&31)]
__global__ __launch_bounds__(256) void k_swz(const float* __restrict__ W, uint4* __restrict__ dst,
                                             int Kc, int S) {
    int t = blockIdx.x * 256 + threadIdx.x;
    int total = Kc * S * 4 * 64;
    if (t >= total) return;
    int L = t & 63;
    int u = t >> 6;
    int nt = u & 3; u >>= 2;
    int s = u % S;
    int kk = u / S;
    int CI = S * 16;
    int c0 = s * 16 + (L >> 5) * 8;
    int f = nt * 32 + (L & 31);
    union { unsigned short e[8]; uint4 v; } uu;
#pragma unroll
    for (int j = 0; j < 8; j++) uu.e[j] = f2b(W[(kk * CI + c0 + j) * 128 + f]);
    dst[t] = uu.v;
}

__global__ __launch_bounds__(256) void k_h1(const float* __restrict__ x,
                                            const float* __restrict__ g1,
                                            const float* __restrict__ be1,
                                            const float* __restrict__ stats,
                                            unsigned short* __restrict__ H1) {
    int i = blockIdx.x * 256 + threadIdx.x;   // < NV*16
    if (i >= NV * 16) return;
    int c4 = (i & 15) * 4;
    float4 v = ((const float4*)x)[i];
    float vv[4] = {v.x, v.y, v.z, v.w};
    ushort4 o;
    unsigned short os[4];
#pragma unroll
    for (int j = 0; j < 4; j++) {
        int c = c4 + j;
        float m = stats[c] * (1.0f / NV);
        float var = stats[64 + c] * (1.0f / NV) - m * m;
        float a = g1[c] * rsqrtf(var + EPSV);
        float b = be1[c] - m * a;
        os[j] = f2b(silu_f(vv[j] * a + b));
    }
    o.x = os[0]; o.y = os[1]; o.z = os[2]; o.w = os[3];
    ((ushort4*)H1)[i] = o;
}

__global__ __launch_bounds__(256) void k_h3(unsigned short* __restrict__ H,
                                            const float* __restrict__ g2,
                                            const float* __restrict__ be2,
                                            const float* __restrict__ stats2) {
    int i = blockIdx.x * 256 + threadIdx.x;   // < NV*16 (uint4 of 8 bf16)
    if (i >= NV * 16) return;
    union { uint4 v; unsigned short e[8]; } uu;
    uu.v = ((const uint4*)H)[i];
    int f0 = (i & 15) * 8;
#pragma unroll
    for (int j = 0; j < 8; j++) {
        int f = f0 + j;
        float m = stats2[f] * (1.0f / NV);
        float var = stats2[128 + f] * (1.0f / NV) - m * m;
        float a = g2[f] * rsqrtf(var + EPSV);
        float b = be2[f] - m * a;
        uu.e[j] = f2b(silu_f(b2f(uu.e[j]) * a + b));
    }
    ((uint4*)H)[i] = uu.v;
}

// ---------------- conv kernels ----------------
// V4 structure: block = 256 thr (4 waves), tile 128 rows x 128 cols.
// Wave w owns rows [n0 + w*32, +32), all 128 cols (acc[4], 64 AGPR).
// Reg-staged weight pipeline (NO vmcnt anywhere — compiler tracks all register deps,
// so spills cannot break correctness):
//   step k: [ds_write W(k+1) regs->LDSN] | [gather A(k+1)->regs, idx(k+2), load W(k+2)->regs]
//           | [ds_read W(k) from LDSC + MFMA with A(k)] | lgkmcnt(0); s_barrier.
// Barrier drains ONLY LDS ops (fast, deterministic). Global loads (A, W, idx) stay in
// flight across the barrier and are waited at their use points by compiler-inserted
// s_waitcnt — a full step of latency cover each.
// LDS RAW: ds_write -> lgkmcnt(0) -> barrier -> ds_read.  LDS WAR: ds_reads complete
// before MFMA issue (operands), hence before the barrier; overwrite is post-barrier.
// Missing neighbors gather the zeroed row NV (branch-free, matches reference mask).

#define C2_STEP(AC, AN, IDXC, IDXN, LDSC, LDSN, KK)                                    \
    {                                                                                  \
        if ((KK) + 1 < 27) {                                                           \
            _Pragma("unroll")                                                          \
            for (int j = 0; j < 8; j++)                                                \
                sB[(LDSN) + (w * 8 + j) * 64 + lane] = wR[j];                          \
        }                                                                              \
        __builtin_amdgcn_sched_barrier(0);                                             \
        {                                                                              \
            int rn_ = ((IDXC) < 0) ? NV : (IDXC);                                      \
            const uint4* pn = (const uint4*)H3 + (long)rn_ * 16;                       \
            _Pragma("unroll")                                                          \
            for (int s = 0; s < 8; s++) AN[s] = pn[s * 2 + h];                         \
        }                                                                              \
        IDXN = nbr[((KK) + 2 < 27 ? (KK) + 2 : 26) * NV + row0c];                      \
        if ((KK) + 2 < 27) {                                                           \
            const uint4* gw = W2b + ((KK) + 2) * 2048 + (w * 8) * 64 + lane;           \
            _Pragma("unroll")                                                          \
            for (int j = 0; j < 8; j++) wR[j] = gw[j * 64];                            \
        }                                                                              \
        __builtin_amdgcn_sched_barrier(0);                                             \
        _Pragma("unroll")                                                              \
        for (int s = 0; s < 8; s++) {                                                  \
            uint4 b0 = sB[(LDSC) + (s * 4 + 0) * 64 + lane];                           \
            uint4 b1v = sB[(LDSC) + (s * 4 + 1) * 64 + lane];                          \
            uint4 b2v = sB[(LDSC) + (s * 4 + 2) * 64 + lane];                          \
            uint4 b3v = sB[(LDSC) + (s * 4 + 3) * 64 + lane];                          \
            acc[0] = MFMA32(bc8(AC[s]), bc8(b0), acc[0]);                              \
            acc[1] = MFMA32(bc8(AC[s]), bc8(b1v), acc[1]);                             \
            acc[2] = MFMA32(bc8(AC[s]), bc8(b2v), acc[2]);                             \
            acc[3] = MFMA32(bc8(AC[s]), bc8(b3v), acc[3]);                             \
        }                                                                              \
        asm volatile("s_waitcnt lgkmcnt(0)" ::: "memory");                             \
        __builtin_amdgcn_s_barrier();                                                  \
        __builtin_amdgcn_sched_barrier(0);                                             \
    }

#define C1_STEP(AC, AN, IDXC, IDXN, LDSC, LDSN, KK)                                    \
    {                                                                                  \
        if ((KK) + 1 < 27) {                                                           \
            _Pragma("unroll")                                                          \
            for (int j = 0; j < 4; j++)                                                \
                sB[(LDSN) + (w * 4 + j) * 64 + lane] = wR[j];                          \
        }                                                                              \
        __builtin_amdgcn_sched_barrier(0);                                             \
        {                                                                              \
            int rn_ = ((IDXC) < 0) ? NV : (IDXC);                                      \
            const uint4* pn = (const uint4*)H1 + (long)rn_ * 8;                        \
            _Pragma("unroll")                                                          \
            for (int s = 0; s < 4; s++) AN[s] = pn[s * 2 + h];                         \
        }                                                                              \
        IDXN = nbr[((KK) + 2 < 27 ? (KK) + 2 : 26) * NV + row0c];                      \
        if ((KK) + 2 < 27) {                                                           \
            const uint4* gw = W1b + ((KK) + 2) * 1024 + (w * 4) * 64 + lane;           \
            _Pragma("unroll")                                                          \
            for (int j = 0; j < 4; j++) wR[j] = gw[j * 64];                            \
        }                                                                              \
        __builtin_amdgcn_sched_barrier(0);                                             \
        _Pragma("unroll")                                                              \
        for (int s = 0; s < 4; s++) {                                                  \
            uint4 b0 = sB[(LDSC) + (s * 4 + 0) * 64 + lane];                           \
            uint4 b1v = sB[(LDSC) + (s * 4 + 1) * 64 + lane];                          \
            uint4 b2v = sB[(LDSC) + (s * 4 + 2) * 64 + lane];                          \
            uint4 b3v = sB[(LDSC) + (s * 4 + 3) * 64 + lane];                          \
            acc[0] = MFMA32(bc8(AC[s]), bc8(b0), acc[0]);                              \
            acc[1] = MFMA32(bc8(AC[s]), bc8(b1v), acc[1]);                             \
            acc[2] = MFMA32(bc8(AC[s]), bc8(b2v), acc[2]);                             \
            acc[3] = MFMA32(bc8(AC[s]), bc8(b3v), acc[3]);                             \
        }                                                                              \
        asm volatile("s_waitcnt lgkmcnt(0)" ::: "memory");                             \
        __builtin_amdgcn_s_barrier();                                                  \
        __builtin_amdgcn_sched_barrier(0);                                             \
    }

#define CD_STEP(AC, AN, IDXC, IDXN, LDSC, LDSN, KK)                                    \
    {                                                                                  \
        if ((KK) + 1 < 8) {                                                            \
            _Pragma("unroll")                                                          \
            for (int j = 0; j < 8; j++)                                                \
                sB[(LDSN) + (w * 8 + j) * 64 + lane] = wR[j];                          \
        }                                                                              \
        __builtin_amdgcn_sched_barrier(0);                                             \
        {                                                                              \
            const uint4* pn = (const uint4*)H4 + (long)(IDXC) * 16;                    \
            _Pragma("unroll")                                                          \
            for (int s = 0; s < 8; s++) AN[s] = pn[s * 2 + h];                         \
        }                                                                              \
        IDXN = nbrd[((KK) + 2 < 8 ? (KK) + 2 : 7) * NDN + row0c];                      \
        if ((KK) + 2 < 8) {                                                            \
            const uint4* gw = Wdb + ((KK) + 2) * 2048 + (w * 8) * 64 + lane;           \
            _Pragma("unroll")                                                          \
            for (int j = 0; j < 8; j++) wR[j] = gw[j * 64];                            \
        }                                                                              \
        __builtin_amdgcn_sched_barrier(0);                                             \
        _Pragma("unroll")                                                              \
        for (int s = 0; s < 8; s++) {                                                  \
            uint4 b0 = sB[(LDSC) + (s * 4 + 0) * 64 + lane];                           \
            uint4 b1v = sB[(LDSC) + (s * 4 + 1) * 64 + lane];                          \
            uint4 b2v = sB[(LDSC) + (s * 4 + 2) * 64 + lane];                          \
            uint4 b3v = sB[(LDSC) + (s * 4 + 3) * 64 + lane];                          \
            acc[0] = MFMA32(bc8(AC[s]), bc8(b0), acc[0]);                              \
            acc[1] = MFMA32(bc8(AC[s]), bc8(b1v), acc[1]);                             \
            acc[2] = MFMA32(bc8(AC[s]), bc8(b2v), acc[2]);                             \
            acc[3] = MFMA32(bc8(AC[s]), bc8(b3v), acc[3]);                             \
        }                                                                              \
        asm volatile("s_waitcnt lgkmcnt(0)" ::: "memory");                             \
        __builtin_amdgcn_s_barrier();                                                  \
        __builtin_amdgcn_sched_barrier(0);                                             \
    }

__global__ __launch_bounds__(256, 3) void k_conv1(const unsigned short* __restrict__ H1,
                                                  const int* __restrict__ nbr,
                                                  const uint4* __restrict__ W1b,
                                                  const float* __restrict__ b1,
                                                  const int* __restrict__ b_idx,
                                                  const float* __restrict__ tp,
                                                  unsigned short* __restrict__ H2,
                                                  float* __restrict__ stats2) {
    extern __shared__ uint4 sB[];                  // [2][1024] double-buffered W1 slab
    __shared__ float ssum[128], ssq[128];
    int tid = threadIdx.x;
    int w = tid >> 6, lane = tid & 63, m = lane & 31, h = lane >> 5;
    int n0 = blockIdx.x * 128;
    int row0 = n0 + w * 32 + m;
    int row0c = row0 < NV ? row0 : NV - 1;
    if (tid < 128) { ssum[tid] = 0.f; ssq[tid] = 0.f; }
    f32x16 z;
#pragma unroll
    for (int r = 0; r < 16; r++) z[r] = 0.f;
    f32x16 acc[4] = {z, z, z, z};
    uint4 aA[4], aB[4], wR[4];
    int idxE = 0, idxO;

    {   // prologue: idx(0), idx(1); load W(0)->wR; gather A(0); write W(0)->buf0; load W(1)->wR
        int idx0 = nbr[row0c];
        idxO = nbr[NV + row0c];
        const uint4* gw = W1b + (w * 4) * 64 + lane;
#pragma unroll
        for (int j = 0; j < 4; j++) wR[j] = gw[j * 64];
        int rn_ = idx0 < 0 ? NV : idx0;
        const uint4* p0 = (const uint4*)H1 + (long)rn_ * 8;
#pragma unroll
        for (int s = 0; s < 4; s++) aA[s] = p0[s * 2 + h];
#pragma unroll
        for (int j = 0; j < 4; j++) sB[(w * 4 + j) * 64 + lane] = wR[j];
        const uint4* gw1 = W1b + 1024 + (w * 4) * 64 + lane;
#pragma unroll
        for (int j = 0; j < 4; j++) wR[j] = gw1[j * 64];
        asm volatile("s_waitcnt lgkmcnt(0)" ::: "memory");
        __builtin_amdgcn_s_barrier();
        __builtin_amdgcn_sched_barrier(0);
    }
    for (int k = 0; k < 27; k += 2) {
        C1_STEP(aA, aB, idxO, idxE, 0, 1024, k);
        if (k + 1 < 27) C1_STEP(aB, aA, idxE, idxO, 1024, 0, (k + 1));
    }

    // epilogue: +b1, time-embed affine, write bf16 h2, accumulate stats2
    int col = m;
    float b1f[4];
#pragma unroll
    for (int nt = 0; nt < 4; nt++) b1f[nt] = b1[nt * 32 + col];
    float sl[4] = {0.f, 0.f, 0.f, 0.f}, ql[4] = {0.f, 0.f, 0.f, 0.f};
#pragma unroll
    for (int r = 0; r < 16; r++) {
        int row = w * 32 + (r & 3) + 8 * (r >> 2) + 4 * h;
        int g = n0 + row;
        if (g < NV) {
            int b = b_idx[g];
            const float* tpb = tp + b * 256;
#pragma unroll
            for (int nt = 0; nt < 4; nt++) {
                int f = nt * 32 + col;
                float val = acc[nt][r] + b1f[nt];
                float h2v = (1.0f + tpb[f]) * val + tpb[128 + f];
                H2[(long)g * 128 + f] = f2b(h2v);
                sl[nt] += h2v; ql[nt] += h2v * h2v;
            }
        }
    }
#pragma unroll
    for (int nt = 0; nt < 4; nt++) {
        int f = nt * 32 + col;
        atomicAdd(&ssum[f], sl[nt]);
        atomicAdd(&ssq[f], ql[nt]);
    }
    __syncthreads();
    if (tid < 128) {
        atomicAdd(&stats2[tid], ssum[tid]);
        atomicAdd(&stats2[128 + tid], ssq[tid]);
    }
}

__global__ __launch_bounds__(256, 2) void k_conv2(const unsigned short* __restrict__ H3,
                                                  const int* __restrict__ nbr,
                                                  const uint4* __restrict__ W2b,
                                                  const float* __restrict__ b2,
                                                  const float* __restrict__ x,
                                                  const uint4* __restrict__ Widb,
                                                  const float* __restrict__ bid,
                                                  unsigned short* __restrict__ H4) {
    extern __shared__ uint4 sB[];                  // [2][2048] double-buffered W2 slab
    int tid = threadIdx.x;
    int w = tid >> 6, lane = tid & 63, m = lane & 31, h = lane >> 5;
    int n0 = blockIdx.x * 128;
    int row0 = n0 + w * 32 + m;
    int row0c = row0 < NV ? row0 : NV - 1;
    f32x16 z;
#pragma unroll
    for (int r = 0; r < 16; r++) z[r] = 0.f;
    f32x16 acc[4] = {z, z, z, z};
    uint4 aA[8], aB[8], wR[8];
    int idxE = 0, idxO;

    {   // prologue
        int idx0 = nbr[row0c];
        idxO = nbr[NV + row0c];
        const uint4* gw = W2b + (w * 8) * 64 + lane;
#pragma unroll
        for (int j = 0; j < 8; j++) wR[j] = gw[j * 64];
        int rn_ = idx0 < 0 ? NV : idx0;
        const uint4* p0 = (const uint4*)H3 + (long)rn_ * 16;
#pragma unroll
        for (int s = 0; s < 8; s++) aA[s] = p0[s * 2 + h];
#pragma unroll
        for (int j = 0; j < 8; j++) sB[(w * 8 + j) * 64 + lane] = wR[j];
        const uint4* gw1 = W2b + 2048 + (w * 8) * 64 + lane;
#pragma unroll
        for (int j = 0; j < 8; j++) wR[j] = gw1[j * 64];
        asm volatile("s_waitcnt lgkmcnt(0)" ::: "memory");
        __builtin_amdgcn_s_barrier();
        __builtin_amdgcn_sched_barrier(0);
    }
    for (int k = 0; k < 27; k += 2) {
        C2_STEP(aA, aB, idxO, idxE, 0, 2048, k);
        if (k + 1 < 27) C2_STEP(aB, aA, idxE, idxO, 2048, 0, (k + 1));
    }

    // idconv: x (fp32, CI=64) @ Wid, register-direct (one-time tail, small B)
    {
        uint4 a0[4];
#pragma unroll
        for (int s = 0; s < 4; s++) {
            union { unsigned short e[8]; uint4 v; } u0;
            u0.v = make_uint4(0, 0, 0, 0);
            if (row0 < NV) {
                const float4* xr = (const float4*)(x + (long)row0 * 64);
                float4 f0 = xr[s * 4 + h * 2], f1 = xr[s * 4 + h * 2 + 1];
                u0.e[0] = f2b(f0.x); u0.e[1] = f2b(f0.y); u0.e[2] = f2b(f0.z); u0.e[3] = f2b(f0.w);
                u0.e[4] = f2b(f1.x); u0.e[5] = f2b(f1.y); u0.e[6] = f2b(f1.z); u0.e[7] = f2b(f1.w);
            }
            a0[s] = u0.v;
        }
#pragma unroll
        for (int s = 0; s < 4; s++) {
#pragma unroll
            for (int nt = 0; nt < 4; nt++) {
                uint4 bv = Widb[(s * 4 + nt) * 64 + lane];
                acc[nt] = MFMA32(bc8(a0[s]), bc8(bv), acc[nt]);
            }
        }
    }
    // epilogue: + b2 + bid, write bf16 h4
    int col = m;
#pragma unroll
    for (int nt = 0; nt < 4; nt++) {
        int f = nt * 32 + col;
        float bias = b2[f] + bid[f];
#pragma unroll
        for (int r = 0; r < 16; r++) {
            int row = w * 32 + (r & 3) + 8 * (r >> 2) + 4 * h;
            int g = n0 + row;
            if (g < NV) H4[(long)g * 128 + f] = f2b(acc[nt][r] + bias);
        }
    }
}

__global__ __launch_bounds__(256, 2) void k_down(const unsigned short* __restrict__ H4,
                                                 const int* __restrict__ nbrd,
                                                 const uint4* __restrict__ Wdb,
                                                 float* __restrict__ out) {
    extern __shared__ uint4 sB[];                  // [2][2048] double-buffered Wd slab
    int tid = threadIdx.x;
    int w = tid >> 6, lane = tid & 63, m = lane & 31, h = lane >> 5;
    int n0 = blockIdx.x * 128;
    int row0 = n0 + w * 32 + m;
    int row0c = row0 < NDN ? row0 : NDN - 1;
    f32x16 z;
#pragma unroll
    for (int r = 0; r < 16; r++) z[r] = 0.f;
    f32x16 acc[4] = {z, z, z, z};
    uint4 aA[8], aB[8], wR[8];
    int idxE = 0, idxO;

    {   // prologue
        int idx0 = nbrd[row0c];
        idxO = nbrd[NDN + row0c];
        const uint4* gw = Wdb + (w * 8) * 64 + lane;
#pragma unroll
        for (int j = 0; j < 8; j++) wR[j] = gw[j * 64];
        const uint4* p0 = (const uint4*)H4 + (long)idx0 * 16;
#pragma unroll
        for (int s = 0; s < 8; s++) aA[s] = p0[s * 2 + h];
#pragma unroll
        for (int j = 0; j < 8; j++) sB[(w * 8 + j) * 64 + lane] = wR[j];
        const uint4* gw1 = Wdb + 2048 + (w * 8) * 64 + lane;
#pragma unroll
        for (int j = 0; j < 8; j++) wR[j] = gw1[j * 64];
        asm volatile("s_waitcnt lgkmcnt(0)" ::: "memory");
        __builtin_amdgcn_s_barrier();
        __builtin_amdgcn_sched_barrier(0);
    }
    for (int k = 0; k < 8; k += 2) {
        CD_STEP(aA, aB, idxO, idxE, 0, 2048, k);
        CD_STEP(aB, aA, idxE, idxO, 2048, 0, (k + 1));
    }

    int col = m;
#pragma unroll
    for (int nt = 0; nt < 4; nt++) {
        int f = nt * 32 + col;
#pragma unroll
        for (int r = 0; r < 16; r++) {
            int row = w * 32 + (r & 3) + 8 * (r >> 2) + 4 * h;
            int g = n0 + row;
            if (g < NDN) out[(long)g * 128 + f] = acc[nt][r];
        }
    }
}

// ---------------- launch ----------------

extern "C" void kernel_launch(void* const* d_in, const int* in_sizes, int n_in,
                              void* d_out, int out_size, void* d_ws, size_t ws_size,
                              hipStream_t stream) {
    const float* x   = (const float*)d_in[0];
    const float* t   = (const float*)d_in[1];
    const int* b_idx = (const int*)d_in[2];
    const int* nbr   = (const int*)d_in[3];
    const int* nbrd  = (const int*)d_in[4];
    const float* g1  = (const float*)d_in[5];
    const float* be1 = (const float*)d_in[6];
    const float* W1  = (const float*)d_in[7];
    const float* b1  = (const float*)d_in[8];
    const float* Wt  = (const float*)d_in[9];
    const float* bt  = (const float*)d_in[10];
    const float* g2  = (const float*)d_in[11];
    const float* be2 = (const float*)d_in[12];
    const float* W2  = (const float*)d_in[13];
    const float* b2  = (const float*)d_in[14];
    const float* Wid = (const float*)d_in[15];
    const float* bid = (const float*)d_in[16];
    const float* Wd  = (const float*)d_in[17];
    float* out = (float*)d_out;

    char* ws = (char*)d_ws;
    float* stats1 = (float*)(ws + OFF_STATS1);
    float* stats2 = (float*)(ws + OFF_STATS2);
    float* tp     = (float*)(ws + OFF_TP);
    uint4* W1b    = (uint4*)(ws + OFF_W1B);
    uint4* W2b    = (uint4*)(ws + OFF_W2B);
    uint4* Wdb    = (uint4*)(ws + OFF_WDB);
    uint4* Widb   = (uint4*)(ws + OFF_WIDB);
    unsigned short* H1 = (unsigned short*)(ws + OFF_H1);
    unsigned short* H2 = (unsigned short*)(ws + OFF_H2);
    unsigned short* H4 = (unsigned short*)(ws + OFF_H4);

    k_zero<<<1, 384, 0, stream>>>((float*)ws);
    k_zrow<<<1, 128, 0, stream>>>(H1, H2);
    k_stats1<<<400, 256, 0, stream>>>(x, stats1);
    k_tp<<<16, 256, 0, stream>>>(t, Wt, bt, tp);
    k_swz<<<108, 256, 0, stream>>>(W1, W1b, 27, 4);   // 27*4*4*64 = 27648
    k_swz<<<216, 256, 0, stream>>>(W2, W2b, 27, 8);   // 55296
    k_swz<<<64, 256, 0, stream>>>(Wd, Wdb, 8, 8);     // 16384
    k_swz<<<4, 256, 0, stream>>>(Wid, Widb, 1, 4);    // 1024
    k_h1<<<12500, 256, 0, stream>>>(x, g1, be1, stats1, H1);
    k_conv1<<<(NV + 127) / 128, 256, 2 * 1024 * 16, stream>>>(H1, nbr, W1b, b1, b_idx, tp, H2, stats2);
    k_h3<<<12500, 256, 0, stream>>>(H2, g2, be2, stats2);
    k_conv2<<<(NV + 127) / 128, 256, 2 * 2048 * 16, stream>>>(H2, nbr, W2b, b2, x, Widb, bid, H4);
    k_down<<<(NDN + 127) / 128, 256, 2 * 2048 * 16, stream>>>(H4, nbrd, Wdb, out);
}

// Round 5
// 918.447 us; speedup vs baseline: 1.3484x; 1.3484x over previous
//
#include <hip/hip_runtime.h>

#define NV 200000
#define NDN 25000
#define EPSV 1e-5f

typedef short bf16x8 __attribute__((ext_vector_type(8)));
typedef float f32x16 __attribute__((ext_vector_type(16)));

static __device__ __forceinline__ float silu_f(float v) { return v / (1.0f + __expf(-v)); }
static __device__ __forceinline__ unsigned short f2b(float f) {
    unsigned u = __float_as_uint(f);
    return (unsigned short)((u + 0x7FFFu + ((u >> 16) & 1u)) >> 16);
}
static __device__ __forceinline__ float b2f(unsigned short h) {
    return __uint_as_float(((unsigned)h) << 16);
}
static __device__ __forceinline__ bf16x8 bc8(uint4 v) { return __builtin_bit_cast(bf16x8, v); }
#define MFMA32(a, b, c) __builtin_amdgcn_mfma_f32_32x32x16_bf16(a, b, c, 0, 0, 0)

// workspace byte offsets
#define OFF_STATS1 0                               // 128 f32 (sum[64], sumsq[64])
#define OFF_STATS2 512                             // 256 f32
#define OFF_TP     4096                            // 16*256 f32
#define OFF_W1B    32768                           // bf16 swizzled 27*64*128
#define OFF_W2B    (OFF_W1B + 27 * 64 * 128 * 2)   // 27*128*128
#define OFF_WDB    (OFF_W2B + 27 * 128 * 128 * 2)  // 8*128*128
#define OFF_WIDB   (OFF_WDB + 8 * 128 * 128 * 2)   // 64*128
#define OFF_H1     (2u << 20)                      // bf16 NV*64
#define OFF_H2     (28u << 20)                     // bf16 NV*128 (h2 then h3 in place)
#define OFF_H4     (80u << 20)                     // bf16 NV*128

// ---------------- small kernels ----------------

__global__ void k_zero(float* p) {
    int i = threadIdx.x;
    if (i < 384) p[i] = 0.0f;
}

__global__ __launch_bounds__(256) void k_stats1(const float* __restrict__ x,
                                                float* __restrict__ stats) {
    int c = threadIdx.x & 63;
    int r0 = blockIdx.x * 4 + (threadIdx.x >> 6);
    float s = 0.f, q = 0.f;
    for (int r = r0; r < NV; r += gridDim.x * 4) {
        float v = x[r * 64 + c];
        s += v; q += v * v;
    }
    __shared__ float rs[256], rq[256];
    rs[threadIdx.x] = s; rq[threadIdx.x] = q;
    __syncthreads();
    if (threadIdx.x < 64) {
        s = rs[threadIdx.x] + rs[threadIdx.x + 64] + rs[threadIdx.x + 128] + rs[threadIdx.x + 192];
        q = rq[threadIdx.x] + rq[threadIdx.x + 64] + rq[threadIdx.x + 128] + rq[threadIdx.x + 192];
        atomicAdd(&stats[c], s);
        atomicAdd(&stats[64 + c], q);
    }
}

__global__ __launch_bounds__(256) void k_tp(const float* __restrict__ t,
                                            const float* __restrict__ Wt,
                                            const float* __restrict__ bt,
                                            float* __restrict__ tp) {
    __shared__ float st[256];
    int b = blockIdx.x, o = threadIdx.x;
    st[o] = silu_f(t[b * 256 + o]);
    __syncthreads();
    float acc = bt[o];
    for (int e = 0; e < 256; e++) acc += st[e] * Wt[e * 256 + o];
    tp[b * 256 + o] = acc;
}

// convert weights fp32 [K][CI][128] -> bf16 fragment-order units:
// unit u = ((k*S + s)*4 + nt)*64 + lane ; elem j: W[k][s*16 + (lane>>5)*8 + j][nt*32 + (lane&31)]
__global__ __launch_bounds__(256) void k_swz(const float* __restrict__ W, uint4* __restrict__ dst,
                                             int Kc, int S) {
    int t = blockIdx.x * 256 + threadIdx.x;
    int total = Kc * S * 4 * 64;
    if (t >= total) return;
    int L = t & 63;
    int u = t >> 6;
    int nt = u & 3; u >>= 2;
    int s = u % S;
    int kk = u / S;
    int CI = S * 16;
    int c0 = s * 16 + (L >> 5) * 8;
    int f = nt * 32 + (L & 31);
    union { unsigned short e[8]; uint4 v; } uu;
#pragma unroll
    for (int j = 0; j < 8; j++) uu.e[j] = f2b(W[(kk * CI + c0 + j) * 128 + f]);
    dst[t] = uu.v;
}

__global__ __launch_bounds__(256) void k_h1(const float* __restrict__ x,
                                            const float* __restrict__ g1,
                                            const float* __restrict__ be1,
                                            const float* __restrict__ stats,
                                            unsigned short* __restrict__ H1) {
    int i = blockIdx.x * 256 + threadIdx.x;   // < NV*16
    if (i >= NV * 16) return;
    int c4 = (i & 15) * 4;
    float4 v = ((const float4*)x)[i];
    float vv[4] = {v.x, v.y, v.z, v.w};
    ushort4 o;
    unsigned short os[4];
#pragma unroll
    for (int j = 0; j < 4; j++) {
        int c = c4 + j;
        float m = stats[c] * (1.0f / NV);
        float var = stats[64 + c] * (1.0f / NV) - m * m;
        float a = g1[c] * rsqrtf(var + EPSV);
        float b = be1[c] - m * a;
        os[j] = f2b(silu_f(vv[j] * a + b));
    }
    o.x = os[0]; o.y = os[1]; o.z = os[2]; o.w = os[3];
    ((ushort4*)H1)[i] = o;
}

__global__ __launch_bounds__(256) void k_h3(unsigned short* __restrict__ H,
                                            const float* __restrict__ g2,
                                            const float* __restrict__ be2,
                                            const float* __restrict__ stats2) {
    int i = blockIdx.x * 256 + threadIdx.x;   // < NV*16 (uint4 of 8 bf16)
    if (i >= NV * 16) return;
    union { uint4 v; unsigned short e[8]; } uu;
    uu.v = ((const uint4*)H)[i];
    int f0 = (i & 15) * 8;
#pragma unroll
    for (int j = 0; j < 8; j++) {
        int f = f0 + j;
        float m = stats2[f] * (1.0f / NV);
        float var = stats2[128 + f] * (1.0f / NV) - m * m;
        float a = g2[f] * rsqrtf(var + EPSV);
        float b = be2[f] - m * a;
        uu.e[j] = f2b(silu_f(b2f(uu.e[j]) * a + b));
    }
    ((uint4*)H)[i] = uu.v;
}

// ---------------- conv kernels ----------------
// V5 structure: block = 256 thr (4 waves), tile 128 rows x 128 cols, BARRIER-FREE.
// Wave w owns rows [n0 + w*32, +32) and ALL 128 cols (acc[4], 64 AGPR) -> minimal
// (fully dedup'd) A-gather traffic. B read per-wave straight from global: the k-slab
// is shared by the block's 4 waves via L1/L2 (W*b is ~1.7 MB, L2-resident).
// NO LDS, NO barriers, NO manual waitcnt in the K-loop: waves free-run, the A(k+1)
// gathers + idx(k+2) issued in step k stay in flight across the step boundary under
// compiler-tracked register dependencies (always correct; spills only cost speed).

#define C2_STEP(AC, AN, IDXC, IDXN, KK)                                                \
    {                                                                                  \
        if ((KK) + 1 < 27) {                                                           \
            const uint4* pn = (const uint4*)H3 + (long)(IDXC) * 16;                    \
            _Pragma("unroll")                                                          \
            for (int s = 0; s < 8; s++) {                                              \
                AN[s] = make_uint4(0, 0, 0, 0);                                        \
                if ((IDXC) >= 0) AN[s] = pn[s * 2 + h];                                \
            }                                                                          \
        }                                                                              \
        IDXN = ((KK) + 2 < 27 && row0 < NV) ? nbr[((KK) + 2) * NV + row0] : -1;        \
        const uint4* gW = W2b + (KK) * 2048;                                           \
        _Pragma("unroll")                                                              \
        for (int s = 0; s < 8; s++) {                                                  \
            uint4 b0 = gW[(s * 4 + 0) * 64 + lane];                                    \
            uint4 b1v = gW[(s * 4 + 1) * 64 + lane];                                   \
            uint4 b2v = gW[(s * 4 + 2) * 64 + lane];                                   \
            uint4 b3v = gW[(s * 4 + 3) * 64 + lane];                                   \
            acc[0] = MFMA32(bc8(AC[s]), bc8(b0), acc[0]);                              \
            acc[1] = MFMA32(bc8(AC[s]), bc8(b1v), acc[1]);                             \
            acc[2] = MFMA32(bc8(AC[s]), bc8(b2v), acc[2]);                             \
            acc[3] = MFMA32(bc8(AC[s]), bc8(b3v), acc[3]);                             \
        }                                                                              \
    }

#define C1_STEP(AC, AN, IDXC, IDXN, KK)                                                \
    {                                                                                  \
        if ((KK) + 1 < 27) {                                                           \
            const uint4* pn = (const uint4*)H1 + (long)(IDXC) * 8;                     \
            _Pragma("unroll")                                                          \
            for (int s = 0; s < 4; s++) {                                              \
                AN[s] = make_uint4(0, 0, 0, 0);                                        \
                if ((IDXC) >= 0) AN[s] = pn[s * 2 + h];                                \
            }                                                                          \
        }                                                                              \
        IDXN = ((KK) + 2 < 27 && row0 < NV) ? nbr[((KK) + 2) * NV + row0] : -1;        \
        const uint4* gW = W1b + (KK) * 1024;                                           \
        _Pragma("unroll")                                                              \
        for (int s = 0; s < 4; s++) {                                                  \
            uint4 b0 = gW[(s * 4 + 0) * 64 + lane];                                    \
            uint4 b1v = gW[(s * 4 + 1) * 64 + lane];                                   \
            uint4 b2v = gW[(s * 4 + 2) * 64 + lane];                                   \
            uint4 b3v = gW[(s * 4 + 3) * 64 + lane];                                   \
            acc[0] = MFMA32(bc8(AC[s]), bc8(b0), acc[0]);                              \
            acc[1] = MFMA32(bc8(AC[s]), bc8(b1v), acc[1]);                             \
            acc[2] = MFMA32(bc8(AC[s]), bc8(b2v), acc[2]);                             \
            acc[3] = MFMA32(bc8(AC[s]), bc8(b3v), acc[3]);                             \
        }                                                                              \
    }

#define CD_STEP(AC, AN, IDXC, IDXN, KK)                                                \
    {                                                                                  \
        if ((KK) + 1 < 8) {                                                            \
            const uint4* pn = (const uint4*)H4 + (long)(IDXC) * 16;                    \
            _Pragma("unroll")                                                          \
            for (int s = 0; s < 8; s++) AN[s] = pn[s * 2 + h];                         \
        }                                                                              \
        IDXN = ((KK) + 2 < 8 && row0 < NDN) ? nbrd[((KK) + 2) * NDN + row0] : 0;       \
        const uint4* gW = Wdb + (KK) * 2048;                                           \
        _Pragma("unroll")                                                              \
        for (int s = 0; s < 8; s++) {                                                  \
            uint4 b0 = gW[(s * 4 + 0) * 64 + lane];                                    \
            uint4 b1v = gW[(s * 4 + 1) * 64 + lane];                                   \
            uint4 b2v = gW[(s * 4 + 2) * 64 + lane];                                   \
            uint4 b3v = gW[(s * 4 + 3) * 64 + lane];                                   \
            acc[0] = MFMA32(bc8(AC[s]), bc8(b0), acc[0]);                              \
            acc[1] = MFMA32(bc8(AC[s]), bc8(b1v), acc[1]);                             \
            acc[2] = MFMA32(bc8(AC[s]), bc8(b2v), acc[2]);                             \
            acc[3] = MFMA32(bc8(AC[s]), bc8(b3v), acc[3]);                             \
        }                                                                              \
    }

__global__ __launch_bounds__(256, 3) void k_conv1(const unsigned short* __restrict__ H1,
                                                  const int* __restrict__ nbr,
                                                  const uint4* __restrict__ W1b,
                                                  const float* __restrict__ b1,
                                                  const int* __restrict__ b_idx,
                                                  const float* __restrict__ tp,
                                                  unsigned short* __restrict__ H2,
                                                  float* __restrict__ stats2) {
    __shared__ float ssum[128], ssq[128];
    int tid = threadIdx.x;
    int w = tid >> 6, lane = tid & 63, m = lane & 31, h = lane >> 5;
    int n0 = blockIdx.x * 128;
    int row0 = n0 + w * 32 + m;
    if (tid < 128) { ssum[tid] = 0.f; ssq[tid] = 0.f; }
    f32x16 z;
#pragma unroll
    for (int r = 0; r < 16; r++) z[r] = 0.f;
    f32x16 acc[4] = {z, z, z, z};
    uint4 aA[4], aB[4];
    int idxE, idxO;

    {   // prologue: idx(0), idx(1); gather A(0)
        int idx0 = (row0 < NV) ? nbr[row0] : -1;
        idxO = (row0 < NV) ? nbr[NV + row0] : -1;
        const uint4* p0 = (const uint4*)H1 + (long)idx0 * 8;
#pragma unroll
        for (int s = 0; s < 4; s++) {
            aA[s] = make_uint4(0, 0, 0, 0);
            if (idx0 >= 0) aA[s] = p0[s * 2 + h];
        }
        idxE = idx0;
    }
    for (int k = 0; k < 27; k += 2) {
        C1_STEP(aA, aB, idxO, idxE, k);
        if (k + 1 < 27) C1_STEP(aB, aA, idxE, idxO, (k + 1));
    }

    // epilogue: +b1, time-embed affine, write bf16 h2, accumulate stats2
    int col = m;
    float b1f[4];
#pragma unroll
    for (int nt = 0; nt < 4; nt++) b1f[nt] = b1[nt * 32 + col];
    float sl[4] = {0.f, 0.f, 0.f, 0.f}, ql[4] = {0.f, 0.f, 0.f, 0.f};
#pragma unroll
    for (int r = 0; r < 16; r++) {
        int row = w * 32 + (r & 3) + 8 * (r >> 2) + 4 * h;
        int g = n0 + row;
        if (g < NV) {
            int b = b_idx[g];
            const float* tpb = tp + b * 256;
#pragma unroll
            for (int nt = 0; nt < 4; nt++) {
                int f = nt * 32 + col;
                float val = acc[nt][r] + b1f[nt];
                float h2v = (1.0f + tpb[f]) * val + tpb[128 + f];
                H2[(long)g * 128 + f] = f2b(h2v);
                sl[nt] += h2v; ql[nt] += h2v * h2v;
            }
        }
    }
#pragma unroll
    for (int nt = 0; nt < 4; nt++) {
        int f = nt * 32 + col;
        atomicAdd(&ssum[f], sl[nt]);
        atomicAdd(&ssq[f], ql[nt]);
    }
    __syncthreads();
    if (tid < 128) {
        atomicAdd(&stats2[tid], ssum[tid]);
        atomicAdd(&stats2[128 + tid], ssq[tid]);
    }
}

__global__ __launch_bounds__(256, 2) void k_conv2(const unsigned short* __restrict__ H3,
                                                  const int* __restrict__ nbr,
                                                  const uint4* __restrict__ W2b,
                                                  const float* __restrict__ b2,
                                                  const float* __restrict__ x,
                                                  const uint4* __restrict__ Widb,
                                                  const float* __restrict__ bid,
                                                  unsigned short* __restrict__ H4) {
    int tid = threadIdx.x;
    int w = tid >> 6, lane = tid & 63, m = lane & 31, h = lane >> 5;
    int n0 = blockIdx.x * 128;
    int row0 = n0 + w * 32 + m;
    f32x16 z;
#pragma unroll
    for (int r = 0; r < 16; r++) z[r] = 0.f;
    f32x16 acc[4] = {z, z, z, z};
    uint4 aA[8], aB[8];
    int idxE, idxO;

    {   // prologue
        int idx0 = (row0 < NV) ? nbr[row0] : -1;
        idxO = (row0 < NV) ? nbr[NV + row0] : -1;
        const uint4* p0 = (const uint4*)H3 + (long)idx0 * 16;
#pragma unroll
        for (int s = 0; s < 8; s++) {
            aA[s] = make_uint4(0, 0, 0, 0);
            if (idx0 >= 0) aA[s] = p0[s * 2 + h];
        }
        idxE = idx0;
    }
    for (int k = 0; k < 27; k += 2) {
        C2_STEP(aA, aB, idxO, idxE, k);
        if (k + 1 < 27) C2_STEP(aB, aA, idxE, idxO, (k + 1));
    }

    // idconv: x (fp32, CI=64) @ Wid, register-direct (one-time tail, small B)
    {
        uint4 a0[4];
#pragma unroll
        for (int s = 0; s < 4; s++) {
            union { unsigned short e[8]; uint4 v; } u0;
            u0.v = make_uint4(0, 0, 0, 0);
            if (row0 < NV) {
                const float4* xr = (const float4*)(x + (long)row0 * 64);
                float4 f0 = xr[s * 4 + h * 2], f1 = xr[s * 4 + h * 2 + 1];
                u0.e[0] = f2b(f0.x); u0.e[1] = f2b(f0.y); u0.e[2] = f2b(f0.z); u0.e[3] = f2b(f0.w);
                u0.e[4] = f2b(f1.x); u0.e[5] = f2b(f1.y); u0.e[6] = f2b(f1.z); u0.e[7] = f2b(f1.w);
            }
            a0[s] = u0.v;
        }
#pragma unroll
        for (int s = 0; s < 4; s++) {
#pragma unroll
            for (int nt = 0; nt < 4; nt++) {
                uint4 bv = Widb[(s * 4 + nt) * 64 + lane];
                acc[nt] = MFMA32(bc8(a0[s]), bc8(bv), acc[nt]);
            }
        }
    }
    // epilogue: + b2 + bid, write bf16 h4
    int col = m;
#pragma unroll
    for (int nt = 0; nt < 4; nt++) {
        int f = nt * 32 + col;
        float bias = b2[f] + bid[f];
#pragma unroll
        for (int r = 0; r < 16; r++) {
            int row = w * 32 + (r & 3) + 8 * (r >> 2) + 4 * h;
            int g = n0 + row;
            if (g < NV) H4[(long)g * 128 + f] = f2b(acc[nt][r] + bias);
        }
    }
}

__global__ __launch_bounds__(256, 2) void k_down(const unsigned short* __restrict__ H4,
                                                 const int* __restrict__ nbrd,
                                                 const uint4* __restrict__ Wdb,
                                                 float* __restrict__ out) {
    int tid = threadIdx.x;
    int w = tid >> 6, lane = tid & 63, m = lane & 31, h = lane >> 5;
    int n0 = blockIdx.x * 128;
    int row0 = n0 + w * 32 + m;
    f32x16 z;
#pragma unroll
    for (int r = 0; r < 16; r++) z[r] = 0.f;
    f32x16 acc[4] = {z, z, z, z};
    uint4 aA[8], aB[8];
    int idxE, idxO;

    {   // prologue
        int idx0 = (row0 < NDN) ? nbrd[row0] : 0;
        idxO = (row0 < NDN) ? nbrd[NDN + row0] : 0;
        const uint4* p0 = (const uint4*)H4 + (long)idx0 * 16;
#pragma unroll
        for (int s = 0; s < 8; s++) aA[s] = p0[s * 2 + h];
        idxE = idx0;
    }
    for (int k = 0; k < 8; k += 2) {
        CD_STEP(aA, aB, idxO, idxE, k);
        CD_STEP(aB, aA, idxE, idxO, (k + 1));
    }

    int col = m;
#pragma unroll
    for (int nt = 0; nt < 4; nt++) {
        int f = nt * 32 + col;
#pragma unroll
        for (int r = 0; r < 16; r++) {
            int row = w * 32 + (r & 3) + 8 * (r >> 2) + 4 * h;
            int g = n0 + row;
            if (g < NDN) out[(long)g * 128 + f] = acc[nt][r];
        }
    }
}

// ---------------- launch ----------------

extern "C" void kernel_launch(void* const* d_in, const int* in_sizes, int n_in,
                              void* d_out, int out_size, void* d_ws, size_t ws_size,
                              hipStream_t stream) {
    const float* x   = (const float*)d_in[0];
    const float* t   = (const float*)d_in[1];
    const int* b_idx = (const int*)d_in[2];
    const int* nbr   = (const int*)d_in[3];
    const int* nbrd  = (const int*)d_in[4];
    const float* g1  = (const float*)d_in[5];
    const float* be1 = (const float*)d_in[6];
    const float* W1  = (const float*)d_in[7];
    const float* b1  = (const float*)d_in[8];
    const float* Wt  = (const float*)d_in[9];
    const float* bt  = (const float*)d_in[10];
    const float* g2  = (const float*)d_in[11];
    const float* be2 = (const float*)d_in[12];
    const float* W2  = (const float*)d_in[13];
    const float* b2  = (const float*)d_in[14];
    const float* Wid = (const float*)d_in[15];
    const float* bid = (const float*)d_in[16];
    const float* Wd  = (const float*)d_in[17];
    float* out = (float*)d_out;

    char* ws = (char*)d_ws;
    float* stats1 = (float*)(ws + OFF_STATS1);
    float* stats2 = (float*)(ws + OFF_STATS2);
    float* tp     = (float*)(ws + OFF_TP);
    uint4* W1b    = (uint4*)(ws + OFF_W1B);
    uint4* W2b    = (uint4*)(ws + OFF_W2B);
    uint4* Wdb    = (uint4*)(ws + OFF_WDB);
    uint4* Widb   = (uint4*)(ws + OFF_WIDB);
    unsigned short* H1 = (unsigned short*)(ws + OFF_H1);
    unsigned short* H2 = (unsigned short*)(ws + OFF_H2);
    unsigned short* H4 = (unsigned short*)(ws + OFF_H4);

    k_zero<<<1, 384, 0, stream>>>((float*)ws);
    k_stats1<<<400, 256, 0, stream>>>(x, stats1);
    k_tp<<<16, 256, 0, stream>>>(t, Wt, bt, tp);
    k_swz<<<108, 256, 0, stream>>>(W1, W1b, 27, 4);   // 27*4*4*64 = 27648
    k_swz<<<216, 256, 0, stream>>>(W2, W2b, 27, 8);   // 55296
    k_swz<<<64, 256, 0, stream>>>(Wd, Wdb, 8, 8);     // 16384
    k_swz<<<4, 256, 0, stream>>>(Wid, Widb, 1, 4);    // 1024
    k_h1<<<12500, 256, 0, stream>>>(x, g1, be1, stats1, H1);
    k_conv1<<<(NV + 127) / 128, 256, 0, stream>>>(H1, nbr, W1b, b1, b_idx, tp, H2, stats2);
    k_h3<<<12500, 256, 0, stream>>>(H2, g2, be2, stats2);
    k_conv2<<<(NV + 127) / 128, 256, 0, stream>>>(H2, nbr, W2b, b2, x, Widb, bid, H4);
    k_down<<<(NDN + 127) / 128, 256, 0, stream>>>(H4, nbrd, Wdb, out);
}

// Round 7
// 728.943 us; speedup vs baseline: 1.6990x; 1.2600x over previous
//
#include <hip/hip_runtime.h>

#define NV 200000
#define NDN 25000
#define EPSV 1e-5f

typedef short bf16x8 __attribute__((ext_vector_type(8)));
typedef float f32x16 __attribute__((ext_vector_type(16)));

static __device__ __forceinline__ float silu_f(float v) { return v / (1.0f + __expf(-v)); }
static __device__ __forceinline__ unsigned short f2b(float f) {
    unsigned u = __float_as_uint(f);
    return (unsigned short)((u + 0x7FFFu + ((u >> 16) & 1u)) >> 16);
}
static __device__ __forceinline__ float b2f(unsigned short h) {
    return __uint_as_float(((unsigned)h) << 16);
}
static __device__ __forceinline__ bf16x8 bc8(uint4 v) { return __builtin_bit_cast(bf16x8, v); }
#define MFMA32(a, b, c) __builtin_amdgcn_mfma_f32_32x32x16_bf16(a, b, c, 0, 0, 0)

// async global->LDS, 16B per lane; LDS dest = wave-uniform base + lane*16, global src per-lane
static __device__ __forceinline__ void gload_lds16(const void* g, void* l) {
    __builtin_amdgcn_global_load_lds((const __attribute__((address_space(1))) unsigned*)(g),
                                     (__attribute__((address_space(3))) unsigned*)(l), 16, 0, 0);
}

// workspace byte offsets
#define OFF_STATS1 0                               // 128 f32 (sum[64], sumsq[64])
#define OFF_STATS2 512                             // 256 f32
#define OFF_TP     4096                            // 16*256 f32
#define OFF_W1B    32768                           // bf16 swizzled 27*64*128
#define OFF_W2B    (OFF_W1B + 27 * 64 * 128 * 2)   // 27*128*128
#define OFF_WDB    (OFF_W2B + 27 * 128 * 128 * 2)  // 8*128*128
#define OFF_WIDB   (OFF_WDB + 8 * 128 * 128 * 2)   // 64*128
#define OFF_H1     (2u << 20)                      // bf16 (NV+1)*64  (row NV = zeros)
#define OFF_H2     (28u << 20)                     // bf16 (NV+1)*128 (row NV = zeros; h2 then h3 in place)
#define OFF_H4     (80u << 20)                     // bf16 NV*128

// ---------------- small kernels ----------------

__global__ void k_zero(float* p) {
    int i = threadIdx.x;
    if (i < 384) p[i] = 0.0f;
}

// zero row NV of H1 (64 bf16) and H2 (128 bf16) — gather target for missing neighbors
__global__ void k_zrow(unsigned short* H1, unsigned short* H2) {
    int t = threadIdx.x;    // 128 threads
    if (t < 64) H1[(long)NV * 64 + t] = 0;
    H2[(long)NV * 128 + t] = 0;
}

__global__ __launch_bounds__(256) void k_stats1(const float* __restrict__ x,
                                                float* __restrict__ stats) {
    int c = threadIdx.x & 63;
    int r0 = blockIdx.x * 4 + (threadIdx.x >> 6);
    float s = 0.f, q = 0.f;
    for (int r = r0; r < NV; r += gridDim.x * 4) {
        float v = x[r * 64 + c];
        s += v; q += v * v;
    }
    __shared__ float rs[256], rq[256];
    rs[threadIdx.x] = s; rq[threadIdx.x] = q;
    __syncthreads();
    if (threadIdx.x < 64) {
        s = rs[threadIdx.x] + rs[threadIdx.x + 64] + rs[threadIdx.x + 128] + rs[threadIdx.x + 192];
        q = rq[threadIdx.x] + rq[threadIdx.x + 64] + rq[threadIdx.x + 128] + rq[threadIdx.x + 192];
        atomicAdd(&stats[c], s);
        atomicAdd(&stats[64 + c], q);
    }
}

__global__ __launch_bounds__(256) void k_tp(const float* __restrict__ t,
                                            const float* __restrict__ Wt,
                                            const float* __restrict__ bt,
                                            float* __restrict__ tp) {
    __shared__ float st[256];
    int b = blockIdx.x, o = threadIdx.x;
    st[o] = silu_f(t[b * 256 + o]);
    __syncthreads();
    float acc = bt[o];
    for (int e = 0; e < 256; e++) acc += st[e] * Wt[e * 256 + o];
    tp[b * 256 + o] = acc;
}

// convert weights fp32 [K][CI][128] -> bf16 fragment-order units:
// unit u = ((k*S + s)*4 + nt)*64 + lane ; elem j: W[k][s*16 + (lane>>5)*8 + j][nt*32 + (lane&31)]
__global__ __launch_bounds__(256) void k_swz(const float* __restrict__ W, uint4* __restrict__ dst,
                                             int Kc, int S) {
    int t = blockIdx.x * 256 + threadIdx.x;
    int total = Kc * S * 4 * 64;
    if (t >= total) return;
    int L = t & 63;
    int u = t >> 6;
    int nt = u & 3; u >>= 2;
    int s = u % S;
    int kk = u / S;
    int CI = S * 16;
    int c0 = s * 16 + (L >> 5) * 8;
    int f = nt * 32 + (L & 31);
    union { unsigned short e[8]; uint4 v; } uu;
#pragma unroll
    for (int j = 0; j < 8; j++) uu.e[j] = f2b(W[(kk * CI + c0 + j) * 128 + f]);
    dst[t] = uu.v;
}

__global__ __launch_bounds__(256) void k_h1(const float* __restrict__ x,
                                            const float* __restrict__ g1,
                                            const float* __restrict__ be1,
                                            const float* __restrict__ stats,
                                            unsigned short* __restrict__ H1) {
    int i = blockIdx.x * 256 + threadIdx.x;   // < NV*16
    if (i >= NV * 16) return;
    int c4 = (i & 15) * 4;
    float4 v = ((const float4*)x)[i];
    float vv[4] = {v.x, v.y, v.z, v.w};
    ushort4 o;
    unsigned short os[4];
#pragma unroll
    for (int j = 0; j < 4; j++) {
        int c = c4 + j;
        float m = stats[c] * (1.0f / NV);
        float var = stats[64 + c] * (1.0f / NV) - m * m;
        float a = g1[c] * rsqrtf(var + EPSV);
        float b = be1[c] - m * a;
        os[j] = f2b(silu_f(vv[j] * a + b));
    }
    o.x = os[0]; o.y = os[1]; o.z = os[2]; o.w = os[3];
    ((ushort4*)H1)[i] = o;
}

__global__ __launch_bounds__(256) void k_h3(unsigned short* __restrict__ H,
                                            const float* __restrict__ g2,
                                            const float* __restrict__ be2,
                                            const float* __restrict__ stats2) {
    int i = blockIdx.x * 256 + threadIdx.x;   // < NV*16 (uint4 of 8 bf16); row NV untouched (stays 0)
    if (i >= NV * 16) return;
    union { uint4 v; unsigned short e[8]; } uu;
    uu.v = ((const uint4*)H)[i];
    int f0 = (i & 15) * 8;
#pragma unroll
    for (int j = 0; j < 8; j++) {
        int f = f0 + j;
        float m = stats2[f] * (1.0f / NV);
        float var = stats2[128 + f] * (1.0f / NV) - m * m;
        float a = g2[f] * rsqrtf(var + EPSV);
        float b = be2[f] - m * a;
        uu.e[j] = f2b(silu_f(b2f(uu.e[j]) * a + b));
    }
    ((uint4*)H)[i] = uu.v;
}

// ---------------- conv1 / down: R2-proven structure (scattered gathers, B dbuf LDS) ----------------

#define C1_STEP(AC, AN, IDXC, IDXN, LDSC, LDSN, KK)                                    \
    {                                                                                  \
        if ((KK) + 1 < 27) {                                                           \
            const uint4* pn = (const uint4*)H1 + (long)(IDXC) * 8;                     \
            _Pragma("unroll")                                                          \
            for (int s = 0; s < 4; s++) {                                              \
                AN[s] = make_uint4(0, 0, 0, 0);                                        \
                if ((IDXC) >= 0) AN[s] = pn[s * 2 + h];                                \
            }                                                                          \
        }                                                                              \
        IDXN = ((KK) + 2 < 27 && row0 < NV) ? nbr[((KK) + 2) * NV + row0] : -1;        \
        if ((KK) + 1 < 27) {                                                           \
            const uint4* gsrc = W1b + ((KK) + 1) * 1024 + (w * 4) * 64 + lane;         \
            _Pragma("unroll")                                                          \
            for (int j = 0; j < 4; j++)                                                \
                gload_lds16(gsrc + j * 64, &sB[(LDSN) + (w * 4 + j) * 64]);            \
        }                                                                              \
        _Pragma("unroll")                                                              \
        for (int s = 0; s < 4; s++) {                                                  \
            uint4 b0 = sB[(LDSC) + (s * 4 + 0) * 64 + lane];                           \
            uint4 b1v = sB[(LDSC) + (s * 4 + 1) * 64 + lane];                          \
            uint4 b2v = sB[(LDSC) + (s * 4 + 2) * 64 + lane];                          \
            uint4 b3v = sB[(LDSC) + (s * 4 + 3) * 64 + lane];                          \
            acc[0] = MFMA32(bc8(AC[s]), bc8(b0), acc[0]);                              \
            acc[1] = MFMA32(bc8(AC[s]), bc8(b1v), acc[1]);                             \
            acc[2] = MFMA32(bc8(AC[s]), bc8(b2v), acc[2]);                             \
            acc[3] = MFMA32(bc8(AC[s]), bc8(b3v), acc[3]);                             \
        }                                                                              \
        __syncthreads();                                                               \
    }

#define CD_STEP(AC, AN, IDXC, IDXN, LDSC, LDSN, KK)                                    \
    {                                                                                  \
        if ((KK) + 1 < 8) {                                                            \
            const uint4* pn = (const uint4*)H4 + (long)(IDXC) * 16;                    \
            _Pragma("unroll")                                                          \
            for (int s = 0; s < 8; s++) AN[s] = pn[s * 2 + h];                         \
        }                                                                              \
        IDXN = ((KK) + 2 < 8 && row0 < NDN) ? nbrd[((KK) + 2) * NDN + row0] : 0;       \
        if ((KK) + 1 < 8) {                                                            \
            const uint4* gsrc = Wdb + ((KK) + 1) * 2048 + (w * 8) * 64 + lane;         \
            _Pragma("unroll")                                                          \
            for (int j = 0; j < 8; j++)                                                \
                gload_lds16(gsrc + j * 64, &sB[(LDSN) + (w * 8 + j) * 64]);            \
        }                                                                              \
        _Pragma("unroll")                                                              \
        for (int s = 0; s < 8; s++) {                                                  \
            uint4 b0 = sB[(LDSC) + (s * 4 + 0) * 64 + lane];                           \
            uint4 b1v = sB[(LDSC) + (s * 4 + 1) * 64 + lane];                          \
            uint4 b2v = sB[(LDSC) + (s * 4 + 2) * 64 + lane];                          \
            uint4 b3v = sB[(LDSC) + (s * 4 + 3) * 64 + lane];                          \
            acc[0] = MFMA32(bc8(AC[s]), bc8(b0), acc[0]);                              \
            acc[1] = MFMA32(bc8(AC[s]), bc8(b1v), acc[1]);                             \
            acc[2] = MFMA32(bc8(AC[s]), bc8(b2v), acc[2]);                             \
            acc[3] = MFMA32(bc8(AC[s]), bc8(b3v), acc[3]);                             \
        }                                                                              \
        __syncthreads();                                                               \
    }

__global__ __launch_bounds__(256, 2) void k_conv1(const unsigned short* __restrict__ H1,
                                                  const int* __restrict__ nbr,
                                                  const uint4* __restrict__ W1b,
                                                  const float* __restrict__ b1,
                                                  const int* __restrict__ b_idx,
                                                  const float* __restrict__ tp,
                                                  unsigned short* __restrict__ H2,
                                                  float* __restrict__ stats2) {
    extern __shared__ uint4 sB[];                  // [2][1024] double-buffered W1 slab
    __shared__ float ssum[128], ssq[128];
    int tid = threadIdx.x;
    int w = tid >> 6, lane = tid & 63, m = lane & 31, h = lane >> 5;
    int n0 = blockIdx.x * 128;
    int row0 = n0 + w * 32 + m;
    if (tid < 128) { ssum[tid] = 0.f; ssq[tid] = 0.f; }
    f32x16 z;
#pragma unroll
    for (int r = 0; r < 16; r++) z[r] = 0.f;
    f32x16 acc[4] = {z, z, z, z};
    uint4 aA[4], aB[4];
    int idxE, idxO;

    {   // prologue: idx(0), idx(1); stage B(0); gather A(0)
        int idx0 = (row0 < NV) ? nbr[row0] : -1;
        idxO = (row0 < NV) ? nbr[NV + row0] : -1;
        const uint4* g0 = W1b + (w * 4) * 64 + lane;
#pragma unroll
        for (int j = 0; j < 4; j++) gload_lds16(g0 + j * 64, &sB[(w * 4 + j) * 64]);
        const uint4* p0 = (const uint4*)H1 + (long)idx0 * 8;
#pragma unroll
        for (int s = 0; s < 4; s++) {
            aA[s] = make_uint4(0, 0, 0, 0);
            if (idx0 >= 0) aA[s] = p0[s * 2 + h];
        }
        idxE = idx0;
        __syncthreads();
    }
    for (int k = 0; k < 27; k += 2) {
        C1_STEP(aA, aB, idxO, idxE, 0, 1024, k);
        if (k + 1 < 27) C1_STEP(aB, aA, idxE, idxO, 1024, 0, (k + 1));
    }

    // epilogue: +b1, time-embed affine, write bf16 h2, accumulate stats2
    int col = m;
    float b1f[4];
#pragma unroll
    for (int nt = 0; nt < 4; nt++) b1f[nt] = b1[nt * 32 + col];
    float sl[4] = {0.f, 0.f, 0.f, 0.f}, ql[4] = {0.f, 0.f, 0.f, 0.f};
#pragma unroll
    for (int r = 0; r < 16; r++) {
        int row = w * 32 + (r & 3) + 8 * (r >> 2) + 4 * h;
        int g = n0 + row;
        if (g < NV) {
            int b = b_idx[g];
            const float* tpb = tp + b * 256;
#pragma unroll
            for (int nt = 0; nt < 4; nt++) {
                int f = nt * 32 + col;
                float val = acc[nt][r] + b1f[nt];
                float h2v = (1.0f + tpb[f]) * val + tpb[128 + f];
                H2[(long)g * 128 + f] = f2b(h2v);
                sl[nt] += h2v; ql[nt] += h2v * h2v;
            }
        }
    }
#pragma unroll
    for (int nt = 0; nt < 4; nt++) {
        int f = nt * 32 + col;
        atomicAdd(&ssum[f], sl[nt]);
        atomicAdd(&ssq[f], ql[nt]);
    }
    __syncthreads();
    if (tid < 128) {
        atomicAdd(&stats2[tid], ssum[tid]);
        atomicAdd(&stats2[128 + tid], ssq[tid]);
    }
}

// ---------------- conv2 V6b: row-coalesced gload_lds A (within-line XOR) + chunked B ----------------
// Block 256 thr / 4 waves; wave w owns rows [n0+w*32,+32), all 128 cols (acc[4]).
// LDS 64KB static: [0,32K) per-wave A (8KB, chunk-recycled); [32K,64K) B slab (32KB, chunk-recycled).
// A staged row-coalesced, swizzle WITHIN each 64B line only (line number == chunk, the V6 bugfix):
//   inst (c,half): lane l (rl=l>>2, w'=l&3) fetches granule (c<<2)|(w'^(rl&3)) of row
//   idx[r0w + half*16 + rl] -> LDS linear (slot c*2048 + half*1024 + rl*64 + w'*16).
//   Each quad reads 4 permuted granules of ONE 64B line -> 16 lines/inst (vs 32-64 scattered).
// Read: granule g of row m lives at c=(g>>2)*2048 + (m>>4)*1024 + (m&15)*64 + ((g&3)^(m&3))*16;
//   compute chunk c uses s=2c,2c+1 -> g>>2==c for ALL lanes -> chunk c reads ONLY A slot c and
//   B units 8c..8c+7; both refilled with k+1 data right after chunk c's barrier. Bank-uniform
//   (8 accesses/bank, verified). Ordering purely via __syncthreads (drains vmcnt — R2-proven).
// Missing neighbors gather the zeroed row NV (matches reference mask semantics).

__global__ __launch_bounds__(256, 2) void k_conv2(const unsigned short* __restrict__ H3,
                                                  const int* __restrict__ nbr,
                                                  const uint4* __restrict__ W2b,
                                                  const float* __restrict__ b2,
                                                  const float* __restrict__ x,
                                                  const uint4* __restrict__ Widb,
                                                  const float* __restrict__ bid,
                                                  unsigned short* __restrict__ H4) {
    __shared__ char lds[65536];
    int tid = threadIdx.x;
    int w = tid >> 6, lane = tid & 63, m = lane & 31, h = lane >> 5;
    int n0 = blockIdx.x * 128;
    int row0 = n0 + w * 32 + m;
    char* Aw = lds + w * 8192;
    char* Bb = lds + 32768;
    int r0w = n0 + w * 32;
    int rA = min(r0w + (lane >> 2), NV - 1);
    int rB = min(r0w + 16 + (lane >> 2), NV - 1);
    int lsw = ((lane & 3) ^ ((lane >> 2) & 3)) << 4;   // within-line XOR swizzle (16B units)
    f32x16 z;
#pragma unroll
    for (int r = 0; r < 16; r++) z[r] = 0.f;
    f32x16 acc[4] = {z, z, z, z};
    int iA = nbr[rA], iB = nbr[rB];        // idx(0)

    {   // prologue: stage A(0) (8 insts) + B(0) (8 insts/wave); load idx(1)
#pragma unroll
        for (int c = 0; c < 4; c++) {
            long s0 = (iA < 0) ? (long)NV : (long)iA;
            long s1 = (iB < 0) ? (long)NV : (long)iB;
            int gsw = (c << 6) | lsw;              // line c (64B) + swizzled granule
            gload_lds16((const char*)H3 + s0 * 256 + gsw, Aw + c * 2048);
            gload_lds16((const char*)H3 + s1 * 256 + gsw, Aw + c * 2048 + 1024);
        }
#pragma unroll
        for (int j = 0; j < 8; j++)
            gload_lds16(W2b + (w * 8 + j) * 64 + lane, Bb + (w * 8 + j) * 1024);
        iA = nbr[NV + rA]; iB = nbr[NV + rB];
        __syncthreads();
    }

    for (int k = 0; k < 27; k++) {
#pragma unroll
        for (int c = 0; c < 4; c++) {
#pragma unroll
            for (int ss = 0; ss < 2; ss++) {
                int s = 2 * c + ss;
                int g = 2 * s + h;                 // g>>2 == c for all lanes
                int wp = (g & 3) ^ (m & 3);
                uint4 fA = *(const uint4*)(Aw + c * 2048 + (m >> 4) * 1024
                                           + (m & 15) * 64 + wp * 16);
                uint4 b0 = *(const uint4*)(Bb + (s * 4 + 0) * 1024 + lane * 16);
                uint4 b1v = *(const uint4*)(Bb + (s * 4 + 1) * 1024 + lane * 16);
                uint4 b2v = *(const uint4*)(Bb + (s * 4 + 2) * 1024 + lane * 16);
                uint4 b3v = *(const uint4*)(Bb + (s * 4 + 3) * 1024 + lane * 16);
                acc[0] = MFMA32(bc8(fA), bc8(b0), acc[0]);
                acc[1] = MFMA32(bc8(fA), bc8(b1v), acc[1]);
                acc[2] = MFMA32(bc8(fA), bc8(b2v), acc[2]);
                acc[3] = MFMA32(bc8(fA), bc8(b3v), acc[3]);
            }
            __syncthreads();
            if (k + 1 < 27) {
                long s0 = (iA < 0) ? (long)NV : (long)iA;
                long s1 = (iB < 0) ? (long)NV : (long)iB;
                int gsw = (c << 6) | lsw;
                gload_lds16((const char*)H3 + s0 * 256 + gsw, Aw + c * 2048);
                gload_lds16((const char*)H3 + s1 * 256 + gsw, Aw + c * 2048 + 1024);
                const uint4* bs = W2b + (k + 1) * 2048 + (8 * c + w * 2) * 64;
                gload_lds16(bs + lane, Bb + (8 * c + w * 2) * 1024);
                gload_lds16(bs + 64 + lane, Bb + (8 * c + w * 2 + 1) * 1024);
            }
        }
        if (k + 2 < 27) { iA = nbr[(k + 2) * NV + rA]; iB = nbr[(k + 2) * NV + rB]; }
    }

    // idconv: x (fp32, CI=64) @ Wid, register-direct (one-time tail, small B)
    {
        uint4 a0[4];
#pragma unroll
        for (int s = 0; s < 4; s++) {
            union { unsigned short e[8]; uint4 v; } u0;
            u0.v = make_uint4(0, 0, 0, 0);
            if (row0 < NV) {
                const float4* xr = (const float4*)(x + (long)row0 * 64);
                float4 f0 = xr[s * 4 + h * 2], f1 = xr[s * 4 + h * 2 + 1];
                u0.e[0] = f2b(f0.x); u0.e[1] = f2b(f0.y); u0.e[2] = f2b(f0.z); u0.e[3] = f2b(f0.w);
                u0.e[4] = f2b(f1.x); u0.e[5] = f2b(f1.y); u0.e[6] = f2b(f1.z); u0.e[7] = f2b(f1.w);
            }
            a0[s] = u0.v;
        }
#pragma unroll
        for (int s = 0; s < 4; s++) {
#pragma unroll
            for (int nt = 0; nt < 4; nt++) {
                uint4 bv = Widb[(s * 4 + nt) * 64 + lane];
                acc[nt] = MFMA32(bc8(a0[s]), bc8(bv), acc[nt]);
            }
        }
    }
    // epilogue: + b2 + bid, write bf16 h4
    int col = m;
#pragma unroll
    for (int nt = 0; nt < 4; nt++) {
        int f = nt * 32 + col;
        float bias = b2[f] + bid[f];
#pragma unroll
        for (int r = 0; r < 16; r++) {
            int row = w * 32 + (r & 3) + 8 * (r >> 2) + 4 * h;
            int g = n0 + row;
            if (g < NV) H4[(long)g * 128 + f] = f2b(acc[nt][r] + bias);
        }
    }
}

__global__ __launch_bounds__(256, 2) void k_down(const unsigned short* __restrict__ H4,
                                                 const int* __restrict__ nbrd,
                                                 const uint4* __restrict__ Wdb,
                                                 float* __restrict__ out) {
    extern __shared__ uint4 sB[];                  // [2][2048] double-buffered Wd slab
    int tid = threadIdx.x;
    int w = tid >> 6, lane = tid & 63, m = lane & 31, h = lane >> 5;
    int n0 = blockIdx.x * 128;
    int row0 = n0 + w * 32 + m;
    f32x16 z;
#pragma unroll
    for (int r = 0; r < 16; r++) z[r] = 0.f;
    f32x16 acc[4] = {z, z, z, z};
    uint4 aA[8], aB[8];
    int idxE, idxO;

    {   // prologue
        int idx0 = (row0 < NDN) ? nbrd[row0] : 0;
        idxO = (row0 < NDN) ? nbrd[NDN + row0] : 0;
        const uint4* g0 = Wdb + (w * 8) * 64 + lane;
#pragma unroll
        for (int j = 0; j < 8; j++) gload_lds16(g0 + j * 64, &sB[(w * 8 + j) * 64]);
        const uint4* p0 = (const uint4*)H4 + (long)idx0 * 16;
#pragma unroll
        for (int s = 0; s < 8; s++) aA[s] = p0[s * 2 + h];
        idxE = idx0;
        __syncthreads();
    }
    for (int k = 0; k < 8; k += 2) {
        CD_STEP(aA, aB, idxO, idxE, 0, 2048, k);
        CD_STEP(aB, aA, idxE, idxO, 2048, 0, (k + 1));
    }

    int col = m;
#pragma unroll
    for (int nt = 0; nt < 4; nt++) {
        int f = nt * 32 + col;
#pragma unroll
        for (int r = 0; r < 16; r++) {
            int row = w * 32 + (r & 3) + 8 * (r >> 2) + 4 * h;
            int g = n0 + row;
            if (g < NDN) out[(long)g * 128 + f] = acc[nt][r];
        }
    }
}

// ---------------- launch ----------------

extern "C" void kernel_launch(void* const* d_in, const int* in_sizes, int n_in,
                              void* d_out, int out_size, void* d_ws, size_t ws_size,
                              hipStream_t stream) {
    const float* x   = (const float*)d_in[0];
    const float* t   = (const float*)d_in[1];
    const int* b_idx = (const int*)d_in[2];
    const int* nbr   = (const int*)d_in[3];
    const int* nbrd  = (const int*)d_in[4];
    const float* g1  = (const float*)d_in[5];
    const float* be1 = (const float*)d_in[6];
    const float* W1  = (const float*)d_in[7];
    const float* b1  = (const float*)d_in[8];
    const float* Wt  = (const float*)d_in[9];
    const float* bt  = (const float*)d_in[10];
    const float* g2  = (const float*)d_in[11];
    const float* be2 = (const float*)d_in[12];
    const float* W2  = (const float*)d_in[13];
    const float* b2  = (const float*)d_in[14];
    const float* Wid = (const float*)d_in[15];
    const float* bid = (const float*)d_in[16];
    const float* Wd  = (const float*)d_in[17];
    float* out = (float*)d_out;

    char* ws = (char*)d_ws;
    float* stats1 = (float*)(ws + OFF_STATS1);
    float* stats2 = (float*)(ws + OFF_STATS2);
    float* tp     = (float*)(ws + OFF_TP);
    uint4* W1b    = (uint4*)(ws + OFF_W1B);
    uint4* W2b    = (uint4*)(ws + OFF_W2B);
    uint4* Wdb    = (uint4*)(ws + OFF_WDB);
    uint4* Widb   = (uint4*)(ws + OFF_WIDB);
    unsigned short* H1 = (unsigned short*)(ws + OFF_H1);
    unsigned short* H2 = (unsigned short*)(ws + OFF_H2);
    unsigned short* H4 = (unsigned short*)(ws + OFF_H4);

    k_zero<<<1, 384, 0, stream>>>((float*)ws);
    k_zrow<<<1, 128, 0, stream>>>(H1, H2);
    k_stats1<<<400, 256, 0, stream>>>(x, stats1);
    k_tp<<<16, 256, 0, stream>>>(t, Wt, bt, tp);
    k_swz<<<108, 256, 0, stream>>>(W1, W1b, 27, 4);   // 27*4*4*64 = 27648
    k_swz<<<216, 256, 0, stream>>>(W2, W2b, 27, 8);   // 55296
    k_swz<<<64, 256, 0, stream>>>(Wd, Wdb, 8, 8);     // 16384
    k_swz<<<4, 256, 0, stream>>>(Wid, Widb, 1, 4);    // 1024
    k_h1<<<12500, 256, 0, stream>>>(x, g1, be1, stats1, H1);
    k_conv1<<<(NV + 127) / 128, 256, 2 * 1024 * 16, stream>>>(H1, nbr, W1b, b1, b_idx, tp, H2, stats2);
    k_h3<<<12500, 256, 0, stream>>>(H2, g2, be2, stats2);
    k_conv2<<<(NV + 127) / 128, 256, 0, stream>>>(H2, nbr, W2b, b2, x, Widb, bid, H4);
    k_down<<<(NDN + 127) / 128, 256, 2 * 2048 * 16, stream>>>(H4, nbrd, Wdb, out);
}

// Round 8
// 663.639 us; speedup vs baseline: 1.8662x; 1.0984x over previous
//
#include <hip/hip_runtime.h>

#define NV 200000
#define NDN 25000
#define EPSV 1e-5f

typedef short bf16x8 __attribute__((ext_vector_type(8)));
typedef float f32x16 __attribute__((ext_vector_type(16)));

static __device__ __forceinline__ float silu_f(float v) { return v / (1.0f + __expf(-v)); }
static __device__ __forceinline__ unsigned short f2b(float f) {
    unsigned u = __float_as_uint(f);
    return (unsigned short)((u + 0x7FFFu + ((u >> 16) & 1u)) >> 16);
}
static __device__ __forceinline__ float b2f(unsigned short h) {
    return __uint_as_float(((unsigned)h) << 16);
}
static __device__ __forceinline__ bf16x8 bc8(uint4 v) { return __builtin_bit_cast(bf16x8, v); }
#define MFMA32(a, b, c) __builtin_amdgcn_mfma_f32_32x32x16_bf16(a, b, c, 0, 0, 0)

// async global->LDS, 16B per lane; dest = wave-uniform base + lane*16
static __device__ __forceinline__ void gload_lds16(const uint4* g, uint4* l) {
    __builtin_amdgcn_global_load_lds((const __attribute__((address_space(1))) unsigned*)(g),
                                     (__attribute__((address_space(3))) unsigned*)(l), 16, 0, 0);
}

// workspace byte offsets
#define OFF_STATS1 0                               // 128 f32 (sum[64], sumsq[64])
#define OFF_STATS2 512                             // 256 f32
#define OFF_TP     4096                            // 16*256 f32
#define OFF_W1B    32768                           // bf16 swizzled 27*64*128
#define OFF_W2B    (OFF_W1B + 27 * 64 * 128 * 2)   // 27*128*128
#define OFF_WDB    (OFF_W2B + 27 * 128 * 128 * 2)  // 8*128*128
#define OFF_WIDB   (OFF_WDB + 8 * 128 * 128 * 2)   // 64*128
#define OFF_H1     (2u << 20)                      // bf16 NV*64
#define OFF_H2     (28u << 20)                     // bf16 NV*128 (h2 then h3 in place)
#define OFF_H4     (80u << 20)                     // bf16 NV*128

// ---------------- fused preprocessing kernel ----------------
// All roles independent; stats buffers pre-zeroed by hipMemsetAsync (stream-ordered).
// blocks [0,108): swz W1 | [108,324): swz W2 | [324,388): swz Wd | [388,392): swz Wid
// blocks [392,408): tp   | [408,808): stats1 (fixed stride 400)

static __device__ __forceinline__ void swz_role(const float* __restrict__ W, uint4* __restrict__ dst,
                                                int Kc, int S, int blk) {
    int t = blk * 256 + threadIdx.x;
    int total = Kc * S * 4 * 64;
    if (t >= total) return;
    int L = t & 63;
    int u = t >> 6;
    int nt = u & 3; u >>= 2;
    int s = u % S;
    int kk = u / S;
    int CI = S * 16;
    int c0 = s * 16 + (L >> 5) * 8;
    int f = nt * 32 + (L & 31);
    union { unsigned short e[8]; uint4 v; } uu;
#pragma unroll
    for (int j = 0; j < 8; j++) uu.e[j] = f2b(W[(kk * CI + c0 + j) * 128 + f]);
    dst[t] = uu.v;
}

__global__ __launch_bounds__(256) void k_pre(const float* __restrict__ x,
                                             const float* __restrict__ t,
                                             const float* __restrict__ Wt,
                                             const float* __restrict__ bt,
                                             const float* __restrict__ W1,
                                             const float* __restrict__ W2,
                                             const float* __restrict__ Wd,
                                             const float* __restrict__ Wid,
                                             float* __restrict__ stats,
                                             float* __restrict__ tp,
                                             uint4* __restrict__ W1b,
                                             uint4* __restrict__ W2b,
                                             uint4* __restrict__ Wdb,
                                             uint4* __restrict__ Widb) {
    __shared__ float shA[256], shB[256];
    int b = blockIdx.x;
    if (b < 108) {
        swz_role(W1, W1b, 27, 4, b);
    } else if (b < 324) {
        swz_role(W2, W2b, 27, 8, b - 108);
    } else if (b < 388) {
        swz_role(Wd, Wdb, 8, 8, b - 324);
    } else if (b < 392) {
        swz_role(Wid, Widb, 1, 4, b - 388);
    } else if (b < 408) {
        int bb = b - 392, o = threadIdx.x;
        shA[o] = silu_f(t[bb * 256 + o]);
        __syncthreads();
        float acc = bt[o];
        for (int e = 0; e < 256; e++) acc += shA[e] * Wt[e * 256 + o];
        tp[bb * 256 + o] = acc;
    } else {
        int bb = b - 408;                        // 400 stats1 blocks, FIXED stride
        int c = threadIdx.x & 63;
        int r0 = bb * 4 + (threadIdx.x >> 6);
        float s = 0.f, q = 0.f;
        for (int r = r0; r < NV; r += 400 * 4) {
            float v = x[r * 64 + c];
            s += v; q += v * v;
        }
        shA[threadIdx.x] = s; shB[threadIdx.x] = q;
        __syncthreads();
        if (threadIdx.x < 64) {
            s = shA[threadIdx.x] + shA[threadIdx.x + 64] + shA[threadIdx.x + 128] + shA[threadIdx.x + 192];
            q = shB[threadIdx.x] + shB[threadIdx.x + 64] + shB[threadIdx.x + 128] + shB[threadIdx.x + 192];
            atomicAdd(&stats[c], s);
            atomicAdd(&stats[64 + c], q);
        }
    }
}

// ---------------- normalization kernels ----------------

__global__ __launch_bounds__(256) void k_h1(const float* __restrict__ x,
                                            const float* __restrict__ g1,
                                            const float* __restrict__ be1,
                                            const float* __restrict__ stats,
                                            unsigned short* __restrict__ H1) {
    int i = blockIdx.x * 256 + threadIdx.x;   // < NV*16
    if (i >= NV * 16) return;
    int c4 = (i & 15) * 4;
    float4 v = ((const float4*)x)[i];
    float vv[4] = {v.x, v.y, v.z, v.w};
    ushort4 o;
    unsigned short os[4];
#pragma unroll
    for (int j = 0; j < 4; j++) {
        int c = c4 + j;
        float m = stats[c] * (1.0f / NV);
        float var = stats[64 + c] * (1.0f / NV) - m * m;
        float a = g1[c] * rsqrtf(var + EPSV);
        float b = be1[c] - m * a;
        os[j] = f2b(silu_f(vv[j] * a + b));
    }
    o.x = os[0]; o.y = os[1]; o.z = os[2]; o.w = os[3];
    ((ushort4*)H1)[i] = o;
}

__global__ __launch_bounds__(256) void k_h3(unsigned short* __restrict__ H,
                                            const float* __restrict__ g2,
                                            const float* __restrict__ be2,
                                            const float* __restrict__ stats2) {
    int i = blockIdx.x * 256 + threadIdx.x;   // < NV*16 (uint4 of 8 bf16)
    if (i >= NV * 16) return;
    union { uint4 v; unsigned short e[8]; } uu;
    uu.v = ((const uint4*)H)[i];
    int f0 = (i & 15) * 8;
#pragma unroll
    for (int j = 0; j < 8; j++) {
        int f = f0 + j;
        float m = stats2[f] * (1.0f / NV);
        float var = stats2[128 + f] * (1.0f / NV) - m * m;
        float a = g2[f] * rsqrtf(var + EPSV);
        float b = be2[f] - m * a;
        uu.e[j] = f2b(silu_f(b2f(uu.e[j]) * a + b));
    }
    ((uint4*)H)[i] = uu.v;
}

// ---------------- conv kernels (R2-proven structure) ----------------
// Block = 256 thr (4 waves), tile 128 rows x 128 cols.
// Wave w owns rows [n0 + w*32, +32), all 128 cols (acc[4], 64 AGPR) -> dedup'd A gathers.
// B k-slab staged once per block into double-buffered LDS via global_load_lds,
// consumed by ds_read_b128. Software pipeline, ONE __syncthreads per k:
//   issue A(k+1) gathers + idx(k+2) + B(k+1) stage; compute k (ds_read+MFMA); barrier.
// Barrier's implicit vmcnt(0) drain = stage-complete guarantee (RAW); barrier orders
// last-iter ds_reads vs next-iter stage writes (WAR).

#define C1_STEP(AC, AN, IDXC, IDXN, LDSC, LDSN, KK)                                    \
    {                                                                                  \
        if ((KK) + 1 < 27) {                                                           \
            const uint4* pn = (const uint4*)H1 + (long)(IDXC) * 8;                     \
            _Pragma("unroll")                                                          \
            for (int s = 0; s < 4; s++) {                                              \
                AN[s] = make_uint4(0, 0, 0, 0);                                        \
                if ((IDXC) >= 0) AN[s] = pn[s * 2 + h];                                \
            }                                                                          \
        }                                                                              \
        IDXN = ((KK) + 2 < 27 && row0 < NV) ? nbr[((KK) + 2) * NV + row0] : -1;        \
        if ((KK) + 1 < 27) {                                                           \
            const uint4* gsrc = W1b + ((KK) + 1) * 1024 + (w * 4) * 64 + lane;         \
            _Pragma("unroll")                                                          \
            for (int j = 0; j < 4; j++)                                                \
                gload_lds16(gsrc + j * 64, &sB[(LDSN) + (w * 4 + j) * 64]);            \
        }                                                                              \
        _Pragma("unroll")                                                              \
        for (int s = 0; s < 4; s++) {                                                  \
            uint4 b0 = sB[(LDSC) + (s * 4 + 0) * 64 + lane];                           \
            uint4 b1v = sB[(LDSC) + (s * 4 + 1) * 64 + lane];                          \
            uint4 b2v = sB[(LDSC) + (s * 4 + 2) * 64 + lane];                          \
            uint4 b3v = sB[(LDSC) + (s * 4 + 3) * 64 + lane];                          \
            acc[0] = MFMA32(bc8(AC[s]), bc8(b0), acc[0]);                              \
            acc[1] = MFMA32(bc8(AC[s]), bc8(b1v), acc[1]);                             \
            acc[2] = MFMA32(bc8(AC[s]), bc8(b2v), acc[2]);                             \
            acc[3] = MFMA32(bc8(AC[s]), bc8(b3v), acc[3]);                             \
        }                                                                              \
        __syncthreads();                                                               \
    }

#define C2_STEP(AC, AN, IDXC, IDXN, LDSC, LDSN, KK)                                    \
    {                                                                                  \
        if ((KK) + 1 < 27) {                                                           \
            const uint4* pn = (const uint4*)H3 + (long)(IDXC) * 16;                    \
            _Pragma("unroll")                                                          \
            for (int s = 0; s < 8; s++) {                                              \
                AN[s] = make_uint4(0, 0, 0, 0);                                        \
                if ((IDXC) >= 0) AN[s] = pn[s * 2 + h];                                \
            }                                                                          \
        }                                                                              \
        IDXN = ((KK) + 2 < 27 && row0 < NV) ? nbr[((KK) + 2) * NV + row0] : -1;        \
        if ((KK) + 1 < 27) {                                                           \
            const uint4* gsrc = W2b + ((KK) + 1) * 2048 + (w * 8) * 64 + lane;         \
            _Pragma("unroll")                                                          \
            for (int j = 0; j < 8; j++)                                                \
                gload_lds16(gsrc + j * 64, &sB[(LDSN) + (w * 8 + j) * 64]);            \
        }                                                                              \
        _Pragma("unroll")                                                              \
        for (int s = 0; s < 8; s++) {                                                  \
            uint4 b0 = sB[(LDSC) + (s * 4 + 0) * 64 + lane];                           \
            uint4 b1v = sB[(LDSC) + (s * 4 + 1) * 64 + lane];                          \
            uint4 b2v = sB[(LDSC) + (s * 4 + 2) * 64 + lane];                          \
            uint4 b3v = sB[(LDSC) + (s * 4 + 3) * 64 + lane];                          \
            acc[0] = MFMA32(bc8(AC[s]), bc8(b0), acc[0]);                              \
            acc[1] = MFMA32(bc8(AC[s]), bc8(b1v), acc[1]);                             \
            acc[2] = MFMA32(bc8(AC[s]), bc8(b2v), acc[2]);                             \
            acc[3] = MFMA32(bc8(AC[s]), bc8(b3v), acc[3]);                             \
        }                                                                              \
        __syncthreads();                                                               \
    }

#define CD_STEP(AC, AN, IDXC, IDXN, LDSC, LDSN, KK)                                    \
    {                                                                                  \
        if ((KK) + 1 < 8) {                                                            \
            const uint4* pn = (const uint4*)H4 + (long)(IDXC) * 16;                    \
            _Pragma("unroll")                                                          \
            for (int s = 0; s < 8; s++) AN[s] = pn[s * 2 + h];                         \
        }                                                                              \
        IDXN = ((KK) + 2 < 8 && row0 < NDN) ? nbrd[((KK) + 2) * NDN + row0] : 0;       \
        if ((KK) + 1 < 8) {                                                            \
            const uint4* gsrc = Wdb + ((KK) + 1) * 2048 + (w * 8) * 64 + lane;         \
            _Pragma("unroll")                                                          \
            for (int j = 0; j < 8; j++)                                                \
                gload_lds16(gsrc + j * 64, &sB[(LDSN) + (w * 8 + j) * 64]);            \
        }                                                                              \
        _Pragma("unroll")                                                              \
        for (int s = 0; s < 8; s++) {                                                  \
            uint4 b0 = sB[(LDSC) + (s * 4 + 0) * 64 + lane];                           \
            uint4 b1v = sB[(LDSC) + (s * 4 + 1) * 64 + lane];                          \
            uint4 b2v = sB[(LDSC) + (s * 4 + 2) * 64 + lane];                          \
            uint4 b3v = sB[(LDSC) + (s * 4 + 3) * 64 + lane];                          \
            acc[0] = MFMA32(bc8(AC[s]), bc8(b0), acc[0]);                              \
            acc[1] = MFMA32(bc8(AC[s]), bc8(b1v), acc[1]);                             \
            acc[2] = MFMA32(bc8(AC[s]), bc8(b2v), acc[2]);                             \
            acc[3] = MFMA32(bc8(AC[s]), bc8(b3v), acc[3]);                             \
        }                                                                              \
        __syncthreads();                                                               \
    }

__global__ __launch_bounds__(256, 2) void k_conv1(const unsigned short* __restrict__ H1,
                                                  const int* __restrict__ nbr,
                                                  const uint4* __restrict__ W1b,
                                                  const float* __restrict__ b1,
                                                  const int* __restrict__ b_idx,
                                                  const float* __restrict__ tp,
                                                  unsigned short* __restrict__ H2,
                                                  float* __restrict__ stats2) {
    extern __shared__ uint4 sB[];                  // [2][1024] double-buffered W1 slab
    __shared__ float ssum[128], ssq[128];
    int tid = threadIdx.x;
    int w = tid >> 6, lane = tid & 63, m = lane & 31, h = lane >> 5;
    int n0 = blockIdx.x * 128;
    int row0 = n0 + w * 32 + m;
    if (tid < 128) { ssum[tid] = 0.f; ssq[tid] = 0.f; }
    f32x16 z;
#pragma unroll
    for (int r = 0; r < 16; r++) z[r] = 0.f;
    f32x16 acc[4] = {z, z, z, z};
    uint4 aA[4], aB[4];
    int idxE, idxO;

    {   // prologue: idx(0), idx(1); stage B(0); gather A(0)
        int idx0 = (row0 < NV) ? nbr[row0] : -1;
        idxO = (row0 < NV) ? nbr[NV + row0] : -1;
        const uint4* g0 = W1b + (w * 4) * 64 + lane;
#pragma unroll
        for (int j = 0; j < 4; j++) gload_lds16(g0 + j * 64, &sB[(w * 4 + j) * 64]);
        const uint4* p0 = (const uint4*)H1 + (long)idx0 * 8;
#pragma unroll
        for (int s = 0; s < 4; s++) {
            aA[s] = make_uint4(0, 0, 0, 0);
            if (idx0 >= 0) aA[s] = p0[s * 2 + h];
        }
        idxE = idx0;
        __syncthreads();
    }
    for (int k = 0; k < 27; k += 2) {
        C1_STEP(aA, aB, idxO, idxE, 0, 1024, k);
        if (k + 1 < 27) C1_STEP(aB, aA, idxE, idxO, 1024, 0, (k + 1));
    }

    // epilogue: +b1, time-embed affine, write bf16 h2, accumulate stats2
    int col = m;
    float b1f[4];
#pragma unroll
    for (int nt = 0; nt < 4; nt++) b1f[nt] = b1[nt * 32 + col];
    float sl[4] = {0.f, 0.f, 0.f, 0.f}, ql[4] = {0.f, 0.f, 0.f, 0.f};
#pragma unroll
    for (int r = 0; r < 16; r++) {
        int row = w * 32 + (r & 3) + 8 * (r >> 2) + 4 * h;
        int g = n0 + row;
        if (g < NV) {
            int b = b_idx[g];
            const float* tpb = tp + b * 256;
#pragma unroll
            for (int nt = 0; nt < 4; nt++) {
                int f = nt * 32 + col;
                float val = acc[nt][r] + b1f[nt];
                float h2v = (1.0f + tpb[f]) * val + tpb[128 + f];
                H2[(long)g * 128 + f] = f2b(h2v);
                sl[nt] += h2v; ql[nt] += h2v * h2v;
            }
        }
    }
#pragma unroll
    for (int nt = 0; nt < 4; nt++) {
        int f = nt * 32 + col;
        atomicAdd(&ssum[f], sl[nt]);
        atomicAdd(&ssq[f], ql[nt]);
    }
    __syncthreads();
    if (tid < 128) {
        atomicAdd(&stats2[tid], ssum[tid]);
        atomicAdd(&stats2[128 + tid], ssq[tid]);
    }
}

__global__ __launch_bounds__(256, 2) void k_conv2(const unsigned short* __restrict__ H3,
                                                  const int* __restrict__ nbr,
                                                  const uint4* __restrict__ W2b,
                                                  const float* __restrict__ b2,
                                                  const float* __restrict__ x,
                                                  const uint4* __restrict__ Widb,
                                                  const float* __restrict__ bid,
                                                  unsigned short* __restrict__ H4) {
    extern __shared__ uint4 sB[];                  // [2][2048] double-buffered W2 slab
    int tid = threadIdx.x;
    int w = tid >> 6, lane = tid & 63, m = lane & 31, h = lane >> 5;
    int n0 = blockIdx.x * 128;
    int row0 = n0 + w * 32 + m;
    f32x16 z;
#pragma unroll
    for (int r = 0; r < 16; r++) z[r] = 0.f;
    f32x16 acc[4] = {z, z, z, z};
    uint4 aA[8], aB[8];
    int idxE, idxO;

    {   // prologue
        int idx0 = (row0 < NV) ? nbr[row0] : -1;
        idxO = (row0 < NV) ? nbr[NV + row0] : -1;
        const uint4* g0 = W2b + (w * 8) * 64 + lane;
#pragma unroll
        for (int j = 0; j < 8; j++) gload_lds16(g0 + j * 64, &sB[(w * 8 + j) * 64]);
        const uint4* p0 = (const uint4*)H3 + (long)idx0 * 16;
#pragma unroll
        for (int s = 0; s < 8; s++) {
            aA[s] = make_uint4(0, 0, 0, 0);
            if (idx0 >= 0) aA[s] = p0[s * 2 + h];
        }
        idxE = idx0;
        __syncthreads();
    }
    for (int k = 0; k < 27; k += 2) {
        C2_STEP(aA, aB, idxO, idxE, 0, 2048, k);
        if (k + 1 < 27) C2_STEP(aB, aA, idxE, idxO, 2048, 0, (k + 1));
    }

    // idconv: x (fp32, CI=64) @ Wid, register-direct (one-time tail, small B)
    {
        uint4 a0[4];
#pragma unroll
        for (int s = 0; s < 4; s++) {
            union { unsigned short e[8]; uint4 v; } u0;
            u0.v = make_uint4(0, 0, 0, 0);
            if (row0 < NV) {
                const float4* xr = (const float4*)(x + (long)row0 * 64);
                float4 f0 = xr[s * 4 + h * 2], f1 = xr[s * 4 + h * 2 + 1];
                u0.e[0] = f2b(f0.x); u0.e[1] = f2b(f0.y); u0.e[2] = f2b(f0.z); u0.e[3] = f2b(f0.w);
                u0.e[4] = f2b(f1.x); u0.e[5] = f2b(f1.y); u0.e[6] = f2b(f1.z); u0.e[7] = f2b(f1.w);
            }
            a0[s] = u0.v;
        }
#pragma unroll
        for (int s = 0; s < 4; s++) {
#pragma unroll
            for (int nt = 0; nt < 4; nt++) {
                uint4 bv = Widb[(s * 4 + nt) * 64 + lane];
                acc[nt] = MFMA32(bc8(a0[s]), bc8(bv), acc[nt]);
            }
        }
    }
    // epilogue: + b2 + bid, write bf16 h4
    int col = m;
#pragma unroll
    for (int nt = 0; nt < 4; nt++) {
        int f = nt * 32 + col;
        float bias = b2[f] + bid[f];
#pragma unroll
        for (int r = 0; r < 16; r++) {
            int row = w * 32 + (r & 3) + 8 * (r >> 2) + 4 * h;
            int g = n0 + row;
            if (g < NV) H4[(long)g * 128 + f] = f2b(acc[nt][r] + bias);
        }
    }
}

__global__ __launch_bounds__(256, 2) void k_down(const unsigned short* __restrict__ H4,
                                                 const int* __restrict__ nbrd,
                                                 const uint4* __restrict__ Wdb,
                                                 float* __restrict__ out) {
    extern __shared__ uint4 sB[];                  // [2][2048] double-buffered Wd slab
    int tid = threadIdx.x;
    int w = tid >> 6, lane = tid & 63, m = lane & 31, h = lane >> 5;
    int n0 = blockIdx.x * 128;
    int row0 = n0 + w * 32 + m;
    f32x16 z;
#pragma unroll
    for (int r = 0; r < 16; r++) z[r] = 0.f;
    f32x16 acc[4] = {z, z, z, z};
    uint4 aA[8], aB[8];
    int idxE, idxO;

    {   // prologue
        int idx0 = (row0 < NDN) ? nbrd[row0] : 0;
        idxO = (row0 < NDN) ? nbrd[NDN + row0] : 0;
        const uint4* g0 = Wdb + (w * 8) * 64 + lane;
#pragma unroll
        for (int j = 0; j < 8; j++) gload_lds16(g0 + j * 64, &sB[(w * 8 + j) * 64]);
        const uint4* p0 = (const uint4*)H4 + (long)idx0 * 16;
#pragma unroll
        for (int s = 0; s < 8; s++) aA[s] = p0[s * 2 + h];
        idxE = idx0;
        __syncthreads();
    }
    for (int k = 0; k < 8; k += 2) {
        CD_STEP(aA, aB, idxO, idxE, 0, 2048, k);
        CD_STEP(aB, aA, idxE, idxO, 2048, 0, (k + 1));
    }

    int col = m;
#pragma unroll
    for (int nt = 0; nt < 4; nt++) {
        int f = nt * 32 + col;
#pragma unroll
        for (int r = 0; r < 16; r++) {
            int row = w * 32 + (r & 3) + 8 * (r >> 2) + 4 * h;
            int g = n0 + row;
            if (g < NDN) out[(long)g * 128 + f] = acc[nt][r];
        }
    }
}

// ---------------- launch ----------------

extern "C" void kernel_launch(void* const* d_in, const int* in_sizes, int n_in,
                              void* d_out, int out_size, void* d_ws, size_t ws_size,
                              hipStream_t stream) {
    const float* x   = (const float*)d_in[0];
    const float* t   = (const float*)d_in[1];
    const int* b_idx = (const int*)d_in[2];
    const int* nbr   = (const int*)d_in[3];
    const int* nbrd  = (const int*)d_in[4];
    const float* g1  = (const float*)d_in[5];
    const float* be1 = (const float*)d_in[6];
    const float* W1  = (const float*)d_in[7];
    const float* b1  = (const float*)d_in[8];
    const float* Wt  = (const float*)d_in[9];
    const float* bt  = (const float*)d_in[10];
    const float* g2  = (const float*)d_in[11];
    const float* be2 = (const float*)d_in[12];
    const float* W2  = (const float*)d_in[13];
    const float* b2  = (const float*)d_in[14];
    const float* Wid = (const float*)d_in[15];
    const float* bid = (const float*)d_in[16];
    const float* Wd  = (const float*)d_in[17];
    float* out = (float*)d_out;

    char* ws = (char*)d_ws;
    float* stats1 = (float*)(ws + OFF_STATS1);
    float* stats2 = (float*)(ws + OFF_STATS2);
    float* tp     = (float*)(ws + OFF_TP);
    uint4* W1b    = (uint4*)(ws + OFF_W1B);
    uint4* W2b    = (uint4*)(ws + OFF_W2B);
    uint4* Wdb    = (uint4*)(ws + OFF_WDB);
    uint4* Widb   = (uint4*)(ws + OFF_WIDB);
    unsigned short* H1 = (unsigned short*)(ws + OFF_H1);
    unsigned short* H2 = (unsigned short*)(ws + OFF_H2);
    unsigned short* H4 = (unsigned short*)(ws + OFF_H4);

    hipMemsetAsync(ws, 0, 4096, stream);   // zero stats1 + stats2
    k_pre<<<808, 256, 0, stream>>>(x, t, Wt, bt, W1, W2, Wd, Wid,
                                   stats1, tp, W1b, W2b, Wdb, Widb);
    k_h1<<<12500, 256, 0, stream>>>(x, g1, be1, stats1, H1);
    k_conv1<<<(NV + 127) / 128, 256, 2 * 1024 * 16, stream>>>(H1, nbr, W1b, b1, b_idx, tp, H2, stats2);
    k_h3<<<12500, 256, 0, stream>>>(H2, g2, be2, stats2);
    k_conv2<<<(NV + 127) / 128, 256, 2 * 2048 * 16, stream>>>(H2, nbr, W2b, b2, x, Widb, bid, H4);
    k_down<<<(NDN + 127) / 128, 256, 2 * 2048 * 16, stream>>>(H4, nbrd, Wdb, out);
}